// Round 12
// baseline (332.069 us; speedup 1.0000x reference)
//
#include <hip/hip_runtime.h>

#define NEG_SLOPE 0.2f
#define EPS_F 1e-16f

#define K_MAX 256          // max buckets (N <= 131072)
#define BCAP 10240         // per-bucket capacity
#define CHUNK 4096         // edges per bin chunk

// instrumentation repeat counts (DIAG round — remove next round)
#define REP_GEMM1 2
#define REP_GAT1  2
#define REP_BIN   5
#define REP_CSR   4
#define REP_GAT2  4

typedef unsigned short u16;
typedef __attribute__((ext_vector_type(8))) short bf16x8;
typedef __attribute__((ext_vector_type(4))) float f32x4;
typedef __attribute__((ext_vector_type(8))) unsigned short ushort8_t;

// round-to-nearest-even f32 -> bf16 (finite inputs)
static __device__ __forceinline__ u16 f2bf(float f) {
    unsigned u = __float_as_uint(f);
    unsigned r = (u + 0x7fffu + ((u >> 16) & 1u)) >> 16;
    return (u16)r;
}
static __device__ __forceinline__ float bflo(unsigned w) { return __uint_as_float(w << 16); }
static __device__ __forceinline__ float bfhi(unsigned w) { return __uint_as_float(w & 0xffff0000u); }

// LDS swizzle for B: XOR col-low-bits into 16B-slot bits (G4)
#define SWZ_B(c, kbyte) ((c) * 512 + ((kbyte) ^ (((c) & 7) << 4)))   // B: [64 cols][256 k] bf16

// ---------------- prep: W1 [256][64] f32 -> w1t [64][256] bf16 ----------------
__global__ __launch_bounds__(256) void prep_w1t_kernel(const float* __restrict__ W1,
                                                       u16* __restrict__ w1t) {
    int t = blockIdx.x * 256 + threadIdx.x;   // 16384 elems
    if (t < 16384) {
        int k = t >> 6, c = t & 63;
        w1t[c * 256 + k] = f2bf(W1[t]);
    }
}

// ---------------- Layer 1 GEMM via MFMA: load-all-then-compute ----------------
__global__ __launch_bounds__(256) void gemm1_kernel(const float* __restrict__ x,
                                                    const u16* __restrict__ w1t,
                                                    const float* __restrict__ a1_src,
                                                    const float* __restrict__ a1_dst,
                                                    u16* __restrict__ h1b,
                                                    float* __restrict__ as1,
                                                    float* __restrict__ ad1, int N) {
    __shared__ u16 ldsB[16384];   // 32 KB: 64 cols x 256 k bf16 (W1^T), swizzled
    const int t = threadIdx.x;
    const int w = t >> 6, l = t & 63;
    const int n0 = blockIdx.x * 64;

    const int r = n0 + w * 16 + (l & 15);
    const int rc = (r < N) ? r : (N - 1);
    const int ksub = (l >> 4) * 8;
    const float* xrow = x + (size_t)rc * 256;

    // stage all of W1^T into LDS once
    {
        int c = t >> 2, q = t & 3;
        #pragma unroll
        for (int i = 0; i < 8; ++i) {
            int kb = q * 128 + i * 16;
            ushort8_t vv = *reinterpret_cast<const ushort8_t*>(&w1t[c * 256 + (kb >> 1)]);
            *reinterpret_cast<ushort8_t*>((char*)ldsB + SWZ_B(c, kb)) = vv;
        }
    }
    __syncthreads();

    float asv[4], adv[4];
    #pragma unroll
    for (int n = 0; n < 4; ++n) {
        int c = n * 16 + (l & 15);
        asv[n] = a1_src[c];
        adv[n] = a1_dst[c];
    }

    #pragma unroll 1
    for (int rep = 0; rep < REP_GEMM1; ++rep) {
        // phase 1: issue ALL 16 x-loads
        float4 va[8], vb[8];
        #pragma unroll
        for (int s = 0; s < 8; ++s) {
            va[s] = *reinterpret_cast<const float4*>(xrow + s * 32 + ksub);
            vb[s] = *reinterpret_cast<const float4*>(xrow + s * 32 + ksub + 4);
        }

        f32x4 acc[4];
        #pragma unroll
        for (int n = 0; n < 4; ++n) acc[n] = (f32x4){0.f, 0.f, 0.f, 0.f};

        // phase 2: convert + MFMA
        #pragma unroll
        for (int s = 0; s < 8; ++s) {
            ushort8_t af;
            af[0] = f2bf(va[s].x); af[1] = f2bf(va[s].y); af[2] = f2bf(va[s].z); af[3] = f2bf(va[s].w);
            af[4] = f2bf(vb[s].x); af[5] = f2bf(vb[s].y); af[6] = f2bf(vb[s].z); af[7] = f2bf(vb[s].w);
            bf16x8 a = *reinterpret_cast<bf16x8*>(&af);
            #pragma unroll
            for (int n = 0; n < 4; ++n) {
                int c = n * 16 + (l & 15);
                bf16x8 b = *reinterpret_cast<bf16x8*>((char*)ldsB + SWZ_B(c, (s * 32 + ksub) * 2));
                acc[n] = __builtin_amdgcn_mfma_f32_16x16x32_bf16(a, b, acc[n], 0, 0, 0);
            }
        }

        // epilogue
        #pragma unroll
        for (int reg = 0; reg < 4; ++reg) {
            int row = n0 + w * 16 + (l >> 4) * 4 + reg;
            bool ok = row < N;
            #pragma unroll
            for (int n = 0; n < 4; ++n) {
                float vv = acc[n][reg];
                if (ok) h1b[(size_t)row * 64 + n * 16 + (l & 15)] = f2bf(vv);
                float s = vv * asv[n];
                float d = vv * adv[n];
                s += __shfl_xor(s, 1); s += __shfl_xor(s, 2); s += __shfl_xor(s, 4);
                d += __shfl_xor(d, 1); d += __shfl_xor(d, 2); d += __shfl_xor(d, 4);
                if (ok && (l & 7) == 0) {
                    int head = n * 2 + ((l & 15) >> 3);
                    as1[row * 8 + head] = s;
                    ad1[row * 8 + head] = d;
                }
            }
        }
    }
}

// ---------------- phase 1: bin edges into dst-buckets ----------------
__global__ __launch_bounds__(256) void bin_kernel(const int* __restrict__ src,
                                                  const int* __restrict__ dst,
                                                  int* __restrict__ cursor_all,
                                                  unsigned* __restrict__ bins_all,
                                                  int E, int K) {
    __shared__ int hist[K_MAX];
    __shared__ int lbase[K_MAX];
    __shared__ int goff[K_MAX];
    __shared__ int rk[K_MAX];
    __shared__ int sc[256];
    __shared__ unsigned pk[CHUNK];
    __shared__ unsigned short bid[CHUNK];

    int t = threadIdx.x;
    int nchunks = (E + CHUNK - 1) / CHUNK;
    #pragma unroll 1
    for (int rep = 0; rep < REP_BIN; ++rep) {
        int* cursor = cursor_all + rep * K_MAX;
        unsigned* bins = bins_all + (size_t)rep * K_MAX * BCAP;
        for (int c = blockIdx.x; c < nchunks; c += gridDim.x) {
            int e0 = c * CHUNK;
            int ne = E - e0; if (ne > CHUNK) ne = CHUNK;
            for (int j = t; j < K_MAX; j += 256) { hist[j] = 0; rk[j] = 0; }
            __syncthreads();

            unsigned pks[16];
            int bks[16];
            #pragma unroll
            for (int k = 0; k < 16; ++k) {
                int i = e0 + t + k * 256;
                if (i < e0 + ne) {
                    int d = dst[i];
                    int s = src[i];
                    int b = d >> 9;
                    pks[k] = ((unsigned)s << 9) | (unsigned)(d & 511);
                    bks[k] = b;
                    atomicAdd(&hist[b], 1);
                } else {
                    bks[k] = -1;
                }
            }
            __syncthreads();
            int hv = (t < K) ? hist[t] : 0;
            int val = hv;
            sc[t] = val; __syncthreads();
            for (int off = 1; off < 256; off <<= 1) {
                int add = (t >= off) ? sc[t - off] : 0;
                __syncthreads();
                val += add; sc[t] = val;
                __syncthreads();
            }
            if (t < K) {
                lbase[t] = val - hv;
                goff[t] = hv ? atomicAdd(&cursor[t], hv) : 0;
            }
            __syncthreads();
            #pragma unroll
            for (int k = 0; k < 16; ++k) {
                if (bks[k] >= 0) {
                    int r = atomicAdd(&rk[bks[k]], 1);
                    int p = lbase[bks[k]] + r;
                    pk[p] = pks[k];
                    bid[p] = (unsigned short)bks[k];
                }
            }
            __syncthreads();
            for (int j = t; j < ne; j += 256) {
                int b = bid[j];
                bins[(size_t)b * BCAP + goff[b] + (j - lbase[b])] = pk[j];
            }
            __syncthreads();
        }
    }
}

// ---------------- phase 2: per-bucket CSR build ----------------
__global__ __launch_bounds__(256) void csr_kernel(const unsigned* __restrict__ bins,
                                                  const int* __restrict__ cursor,
                                                  int* __restrict__ row_ptr,
                                                  int* __restrict__ csr_src,
                                                  int N, int K, int E) {
    __shared__ unsigned pk[BCAP];
    __shared__ int hist[512];
    __shared__ int ex[512];
    __shared__ int rk2[512];
    __shared__ int sc[256];
    __shared__ int bb[256];
    int b = blockIdx.x;
    int t = threadIdx.x;

    #pragma unroll 1
    for (int rep = 0; rep < REP_CSR; ++rep) {
        __syncthreads();
        int cv = (t < K) ? cursor[t] : 0;
        int val = cv;
        sc[t] = val; __syncthreads();
        for (int off = 1; off < 256; off <<= 1) {
            int add = (t >= off) ? sc[t - off] : 0;
            __syncthreads();
            val += add; sc[t] = val;
            __syncthreads();
        }
        bb[t] = val;
        __syncthreads();
        int base_g = (b == 0) ? 0 : bb[b - 1];
        int cnt = cursor[b];
        if (b == K - 1 && t == 0) row_ptr[N] = E;
        __syncthreads();

        for (int j = t; j < cnt; j += 256) pk[j] = bins[(size_t)b * BCAP + j];
        for (int j = t; j < 512; j += 256) { hist[j] = 0; rk2[j] = 0; }
        __syncthreads();
        for (int j = t; j < cnt; j += 256) atomicAdd(&hist[pk[j] & 511u], 1);
        __syncthreads();
        int h0 = hist[2 * t], h1v = hist[2 * t + 1];
        int s = h0 + h1v;
        int v2 = s;
        sc[t] = v2; __syncthreads();
        for (int off = 1; off < 256; off <<= 1) {
            int add = (t >= off) ? sc[t - off] : 0;
            __syncthreads();
            v2 += add; sc[t] = v2;
            __syncthreads();
        }
        int excl = v2 - s;
        ex[2 * t] = excl;
        ex[2 * t + 1] = excl + h0;
        __syncthreads();
        int nd0 = b << 9;
        for (int ld = t; ld < 512; ld += 256) {
            int d = nd0 + ld;
            if (d < N) row_ptr[d] = base_g + ex[ld];
        }
        for (int j = t; j < cnt; j += 256) {
            unsigned w = pk[j];
            int ld = (int)(w & 511u);
            int r = atomicAdd(&rk2[ld], 1);
            csr_src[base_g + ex[ld] + r] = (int)(w >> 9);
        }
    }
}

// ---------------- layer-1 gather: 8 lanes/edge x 8 slots ----------------
__global__ __launch_bounds__(128) void gat1_kernel(const u16* __restrict__ h1b,
                                                   const float* __restrict__ as1,
                                                   const float* __restrict__ ad1,
                                                   const int* __restrict__ row_ptr,
                                                   const int* __restrict__ csr_src,
                                                   const float* __restrict__ b1,
                                                   float* __restrict__ h2, int N) {
    int dst = blockIdx.x * 2 + (threadIdx.x >> 6);
    if (dst >= N) return;
    int lane = threadIdx.x & 63;
    int slot = lane >> 3;
    int d8 = lane & 7;
    float ad = ad1[dst * 8 + d8];
    int start = row_ptr[dst], end = row_ptr[dst + 1];
    #pragma unroll 1
    for (int rep = 0; rep < REP_GAT1; ++rep) {
        float ac0 = 0.f, ac1 = 0.f, ac2 = 0.f, ac3 = 0.f;
        float ac4 = 0.f, ac5 = 0.f, ac6 = 0.f, ac7 = 0.f;
        float ssum = 0.f;
        int i = start;
        while (i < end) {
            int nb = end - i; if (nb > 64) nb = 64;
            int sreg = (lane < nb) ? csr_src[i + lane] : 0;
            int nb16 = nb & ~15;
            int k = 0;
            for (; k < nb16; k += 16) {
                int sv0 = __shfl(sreg, k + slot);
                int sv1 = __shfl(sreg, k + 8 + slot);
                uint4 w0 = *reinterpret_cast<const uint4*>(&h1b[(size_t)sv0 * 64 + d8 * 8]);
                float av0 = as1[sv0 * 8 + d8];
                uint4 w1 = *reinterpret_cast<const uint4*>(&h1b[(size_t)sv1 * 64 + d8 * 8]);
                float av1 = as1[sv1 * 8 + d8];
                float e0 = av0 + ad; e0 = fmaxf(e0, NEG_SLOPE * e0);
                float e1 = av1 + ad; e1 = fmaxf(e1, NEG_SLOPE * e1);
                float x0 = __expf(e0);
                float x1 = __expf(e1);
                ac0 = fmaf(x0, bflo(w0.x), ac0); ac1 = fmaf(x0, bfhi(w0.x), ac1);
                ac2 = fmaf(x0, bflo(w0.y), ac2); ac3 = fmaf(x0, bfhi(w0.y), ac3);
                ac4 = fmaf(x0, bflo(w0.z), ac4); ac5 = fmaf(x0, bfhi(w0.z), ac5);
                ac6 = fmaf(x0, bflo(w0.w), ac6); ac7 = fmaf(x0, bfhi(w0.w), ac7);
                ssum += x0;
                ac0 = fmaf(x1, bflo(w1.x), ac0); ac1 = fmaf(x1, bfhi(w1.x), ac1);
                ac2 = fmaf(x1, bflo(w1.y), ac2); ac3 = fmaf(x1, bfhi(w1.y), ac3);
                ac4 = fmaf(x1, bflo(w1.z), ac4); ac5 = fmaf(x1, bfhi(w1.z), ac5);
                ac6 = fmaf(x1, bflo(w1.w), ac6); ac7 = fmaf(x1, bfhi(w1.w), ac7);
                ssum += x1;
            }
            for (; k < nb; k += 8) {
                int idx = k + slot;
                bool ok = idx < nb;
                int ridx = ok ? idx : nb - 1;
                int sv = __shfl(sreg, ridx);
                uint4 wv = *reinterpret_cast<const uint4*>(&h1b[(size_t)sv * 64 + d8 * 8]);
                float a = as1[sv * 8 + d8];
                float e = a + ad;
                e = fmaxf(e, NEG_SLOPE * e);
                float xx = ok ? __expf(e) : 0.f;
                ac0 = fmaf(xx, bflo(wv.x), ac0); ac1 = fmaf(xx, bfhi(wv.x), ac1);
                ac2 = fmaf(xx, bflo(wv.y), ac2); ac3 = fmaf(xx, bfhi(wv.y), ac3);
                ac4 = fmaf(xx, bflo(wv.z), ac4); ac5 = fmaf(xx, bfhi(wv.z), ac5);
                ac6 = fmaf(xx, bflo(wv.w), ac6); ac7 = fmaf(xx, bfhi(wv.w), ac7);
                ssum += xx;
            }
            i += nb;
        }
        ac0 += __shfl_xor(ac0, 8); ac0 += __shfl_xor(ac0, 16); ac0 += __shfl_xor(ac0, 32);
        ac1 += __shfl_xor(ac1, 8); ac1 += __shfl_xor(ac1, 16); ac1 += __shfl_xor(ac1, 32);
        ac2 += __shfl_xor(ac2, 8); ac2 += __shfl_xor(ac2, 16); ac2 += __shfl_xor(ac2, 32);
        ac3 += __shfl_xor(ac3, 8); ac3 += __shfl_xor(ac3, 16); ac3 += __shfl_xor(ac3, 32);
        ac4 += __shfl_xor(ac4, 8); ac4 += __shfl_xor(ac4, 16); ac4 += __shfl_xor(ac4, 32);
        ac5 += __shfl_xor(ac5, 8); ac5 += __shfl_xor(ac5, 16); ac5 += __shfl_xor(ac5, 32);
        ac6 += __shfl_xor(ac6, 8); ac6 += __shfl_xor(ac6, 16); ac6 += __shfl_xor(ac6, 32);
        ac7 += __shfl_xor(ac7, 8); ac7 += __shfl_xor(ac7, 16); ac7 += __shfl_xor(ac7, 32);
        ssum += __shfl_xor(ssum, 8); ssum += __shfl_xor(ssum, 16); ssum += __shfl_xor(ssum, 32);
        if (slot == 0) {
            float4 bb0 = *reinterpret_cast<const float4*>(&b1[d8 * 8]);
            float4 bb1 = *reinterpret_cast<const float4*>(&b1[d8 * 8 + 4]);
            float inv = 1.f / (ssum + EPS_F);
            float o0 = ac0 * inv + bb0.x;
            float o1 = ac1 * inv + bb0.y;
            float o2 = ac2 * inv + bb0.z;
            float o3 = ac3 * inv + bb0.w;
            float o4 = ac4 * inv + bb1.x;
            float o5 = ac5 * inv + bb1.y;
            float o6 = ac6 * inv + bb1.z;
            float o7 = ac7 * inv + bb1.w;
            o0 = (o0 > 0.f) ? o0 : (__expf(o0) - 1.f);
            o1 = (o1 > 0.f) ? o1 : (__expf(o1) - 1.f);
            o2 = (o2 > 0.f) ? o2 : (__expf(o2) - 1.f);
            o3 = (o3 > 0.f) ? o3 : (__expf(o3) - 1.f);
            o4 = (o4 > 0.f) ? o4 : (__expf(o4) - 1.f);
            o5 = (o5 > 0.f) ? o5 : (__expf(o5) - 1.f);
            o6 = (o6 > 0.f) ? o6 : (__expf(o6) - 1.f);
            o7 = (o7 > 0.f) ? o7 : (__expf(o7) - 1.f);
            *reinterpret_cast<float4*>(&h2[(size_t)dst * 64 + d8 * 8]) = make_float4(o0, o1, o2, o3);
            *reinterpret_cast<float4*>(&h2[(size_t)dst * 64 + d8 * 8 + 4]) = make_float4(o4, o5, o6, o7);
        }
    }
}

// ---------------- Layer 2 GEMM ----------------
__global__ __launch_bounds__(256) void gemm2_kernel(const float* __restrict__ h2,
                                                    const float* __restrict__ W2,
                                                    const float* __restrict__ a2_src,
                                                    const float* __restrict__ a2_dst,
                                                    u16* __restrict__ g2b,
                                                    float* __restrict__ as2,
                                                    float* __restrict__ ad2, int N) {
    __shared__ float hs[64][68];
    __shared__ float ws[1024];
    int t = threadIdx.x;
    int n0 = blockIdx.x * 64;
    *reinterpret_cast<float4*>(&ws[t * 4]) = *reinterpret_cast<const float4*>(&W2[t * 4]);
    #pragma unroll
    for (int ii = 0; ii < 4; ++ii) {
        int fidx = (ii * 256 + t) * 4;
        int row = fidx >> 6;
        int col = fidx & 63;
        float4 v = make_float4(0.f, 0.f, 0.f, 0.f);
        if (n0 + row < N) v = *reinterpret_cast<const float4*>(&h2[(size_t)(n0 + row) * 64 + col]);
        *reinterpret_cast<float4*>(&hs[row][col]) = v;
    }
    __syncthreads();
    int node = t >> 2, j4 = t & 3;
    float4 acc = make_float4(0.f, 0.f, 0.f, 0.f);
    #pragma unroll
    for (int k = 0; k < 64; ++k) {
        float hk = hs[node][k];
        float4 w = *reinterpret_cast<const float4*>(&ws[k * 16 + j4 * 4]);
        acc.x = fmaf(hk, w.x, acc.x);
        acc.y = fmaf(hk, w.y, acc.y);
        acc.z = fmaf(hk, w.z, acc.z);
        acc.w = fmaf(hk, w.w, acc.w);
    }
    float4 asv = *reinterpret_cast<const float4*>(&a2_src[j4 * 4]);
    float4 adv = *reinterpret_cast<const float4*>(&a2_dst[j4 * 4]);
    float ps = acc.x * asv.x + acc.y * asv.y + acc.z * asv.z + acc.w * asv.w;
    float pd = acc.x * adv.x + acc.y * adv.y + acc.z * adv.z + acc.w * adv.w;
    ps += __shfl_xor(ps, 1); ps += __shfl_xor(ps, 2);
    pd += __shfl_xor(pd, 1); pd += __shfl_xor(pd, 2);
    int gnode = n0 + node;
    if (gnode < N) {
        ushort4 p;
        p.x = f2bf(acc.x); p.y = f2bf(acc.y);
        p.z = f2bf(acc.z); p.w = f2bf(acc.w);
        *reinterpret_cast<ushort4*>(&g2b[(size_t)gnode * 16 + j4 * 4]) = p;
        if (j4 == 0) { as2[gnode] = ps; ad2[gnode] = pd; }
    }
}

// ---------------- layer-2 gather + bias + log_softmax ----------------
__global__ __launch_bounds__(128) void gat2_kernel(const u16* __restrict__ g2b,
                                                   const float* __restrict__ as2,
                                                   const float* __restrict__ ad2,
                                                   const int* __restrict__ row_ptr,
                                                   const int* __restrict__ csr_src,
                                                   const float* __restrict__ b2,
                                                   float* __restrict__ out, int N) {
    int dst = blockIdx.x * 2 + (threadIdx.x >> 6);
    if (dst >= N) return;
    int lane = threadIdx.x & 63;
    int slot = lane >> 3, jd = lane & 7;
    float ad = ad2[dst];
    int start = row_ptr[dst], end = row_ptr[dst + 1];
    #pragma unroll 1
    for (int rep = 0; rep < REP_GAT2; ++rep) {
        float acc0 = 0.f, acc1 = 0.f, ssum = 0.f;
        for (int base = start; base < end; base += 16) {
            #pragma unroll
            for (int g = 0; g < 2; ++g) {
                int idx = base + g * 8 + slot;
                bool ok = idx < end;
                int sidx = ok ? idx : end - 1;
                int s = csr_src[sidx];
                unsigned w = *reinterpret_cast<const unsigned*>(&g2b[(size_t)s * 16 + jd * 2]);
                float a = as2[s];
                float e = a + ad;
                e = fmaxf(e, NEG_SLOPE * e);
                float x = ok ? __expf(e) : 0.f;
                acc0 = fmaf(x, bflo(w), acc0);
                acc1 = fmaf(x, bfhi(w), acc1);
                ssum += x;
            }
        }
        acc0 += __shfl_xor(acc0, 8); acc0 += __shfl_xor(acc0, 16); acc0 += __shfl_xor(acc0, 32);
        acc1 += __shfl_xor(acc1, 8); acc1 += __shfl_xor(acc1, 16); acc1 += __shfl_xor(acc1, 32);
        ssum += __shfl_xor(ssum, 8); ssum += __shfl_xor(ssum, 16); ssum += __shfl_xor(ssum, 32);
        float inv = 1.f / (ssum + EPS_F);
        float2 bb = *reinterpret_cast<const float2*>(&b2[jd * 2]);
        float v0 = acc0 * inv + bb.x;
        float v1 = acc1 * inv + bb.y;
        float mm = fmaxf(v0, v1);
        mm = fmaxf(mm, __shfl_xor(mm, 1));
        mm = fmaxf(mm, __shfl_xor(mm, 2));
        mm = fmaxf(mm, __shfl_xor(mm, 4));
        float es = __expf(v0 - mm) + __expf(v1 - mm);
        es += __shfl_xor(es, 1); es += __shfl_xor(es, 2); es += __shfl_xor(es, 4);
        float lse = mm + __logf(es);
        if (lane < 8) {
            *reinterpret_cast<float2*>(&out[(size_t)dst * 16 + jd * 2]) = make_float2(v0, v1);
            *reinterpret_cast<float2*>(&out[(size_t)N * 16 + (size_t)dst * 16 + jd * 2]) =
                make_float2(v0 - lse, v1 - lse);
        }
    }
}

extern "C" void kernel_launch(void* const* d_in, const int* in_sizes, int n_in,
                              void* d_out, int out_size, void* d_ws, size_t ws_size,
                              hipStream_t stream) {
    const float* x      = (const float*)d_in[0];
    const int*   eidx   = (const int*)d_in[1];
    const float* W1     = (const float*)d_in[2];
    const float* a1_src = (const float*)d_in[3];
    const float* a1_dst = (const float*)d_in[4];
    const float* b1     = (const float*)d_in[5];
    const float* W2     = (const float*)d_in[6];
    const float* a2_src = (const float*)d_in[7];
    const float* a2_dst = (const float*)d_in[8];
    const float* b2     = (const float*)d_in[9];

    const int N = in_sizes[0] / 256;
    const int E = in_sizes[1] / 2;
    const int K = (N + 511) >> 9;
    const int* esrc = eidx;
    const int* edst = eidx + E;

    char* ws = (char*)d_ws;
    size_t off = 0;
    auto alloc = [&](size_t bytes) -> void* {
        void* p = ws + off;
        off += (bytes + 255) & ~size_t(255);
        return p;
    };
    u16* h1b         = (u16*)alloc((size_t)N * 64 * 2);
    u16* w1t         = (u16*)alloc((size_t)64 * 256 * 2);
    float* as1       = (float*)alloc((size_t)N * 8 * 4);
    float* ad1       = (float*)alloc((size_t)N * 8 * 4);
    float* h2        = (float*)alloc((size_t)N * 64 * 4);
    u16* g2b         = (u16*)alloc((size_t)N * 16 * 2);
    float* as2       = (float*)alloc((size_t)N * 4);
    float* ad2       = (float*)alloc((size_t)N * 4);
    int* row_ptr     = (int*)alloc((size_t)(N + 1) * 4);
    int* csr_src     = (int*)alloc((size_t)E * 4);
    int* cursor      = (int*)alloc((size_t)REP_BIN * K_MAX * 4);
    unsigned* bins   = (unsigned*)alloc((size_t)REP_BIN * K_MAX * BCAP * 4);

    hipMemsetAsync(cursor, 0, (size_t)REP_BIN * K_MAX * 4, stream);

    prep_w1t_kernel<<<64, 256, 0, stream>>>(W1, w1t);
    gemm1_kernel<<<(N + 63) / 64, 256, 0, stream>>>(x, w1t, a1_src, a1_dst, h1b, as1, ad1, N);
    bin_kernel<<<(E + CHUNK - 1) / CHUNK, 256, 0, stream>>>(esrc, edst, cursor, bins, E, K);
    csr_kernel<<<K, 256, 0, stream>>>(bins, cursor, row_ptr, csr_src, N, K, E);
    gat1_kernel<<<(N + 1) / 2, 128, 0, stream>>>(h1b, as1, ad1, row_ptr, csr_src, b1, h2, N);
    gemm2_kernel<<<(N + 63) / 64, 256, 0, stream>>>(h2, W2, a2_src, a2_dst, g2b, as2, ad2, N);
    gat2_kernel<<<(N + 1) / 2, 128, 0, stream>>>(g2b, as2, ad2, row_ptr, csr_src, b2, (float*)d_out, N);
}

// Round 13
// 191.009 us; speedup vs baseline: 1.7385x; 1.7385x over previous
//
#include <hip/hip_runtime.h>

#define NEG_SLOPE 0.2f
#define EPS_F 1e-16f

#define K_MAX 256          // max buckets (N <= 131072)
#define BCAP 10240         // per-bucket capacity
#define CHUNK 4096         // edges per bin chunk

typedef unsigned short u16;
typedef __attribute__((ext_vector_type(8))) short bf16x8;
typedef __attribute__((ext_vector_type(4))) float f32x4;
typedef __attribute__((ext_vector_type(8))) unsigned short ushort8_t;

// round-to-nearest-even f32 -> bf16 (finite inputs)
static __device__ __forceinline__ u16 f2bf(float f) {
    unsigned u = __float_as_uint(f);
    unsigned r = (u + 0x7fffu + ((u >> 16) & 1u)) >> 16;
    return (u16)r;
}
static __device__ __forceinline__ float bflo(unsigned w) { return __uint_as_float(w << 16); }
static __device__ __forceinline__ float bfhi(unsigned w) { return __uint_as_float(w & 0xffff0000u); }

// LDS swizzle for B: XOR col-low-bits into 16B-slot bits (G4)
#define SWZ_B(c, kbyte) ((c) * 512 + ((kbyte) ^ (((c) & 7) << 4)))   // B: [64 cols][256 k] bf16

// ---------------- prep: W1 -> w1t bf16 transpose, + zero cursor ----------------
__global__ __launch_bounds__(256) void prep_w1t_kernel(const float* __restrict__ W1,
                                                       u16* __restrict__ w1t,
                                                       int* __restrict__ cursor) {
    if (blockIdx.x == 0) cursor[threadIdx.x] = 0;     // K_MAX == blockDim
    int t = blockIdx.x * 256 + threadIdx.x;   // 16384 elems
    if (t < 16384) {
        int k = t >> 6, c = t & 63;
        w1t[c * 256 + k] = f2bf(W1[t]);
    }
}

// ---------------- Layer 1 GEMM via MFMA: load-all-then-compute ----------------
__global__ __launch_bounds__(256) void gemm1_kernel(const float* __restrict__ x,
                                                    const u16* __restrict__ w1t,
                                                    const float* __restrict__ a1_src,
                                                    const float* __restrict__ a1_dst,
                                                    u16* __restrict__ h1b,
                                                    float* __restrict__ as1,
                                                    float* __restrict__ ad1, int N) {
    __shared__ u16 ldsB[16384];   // 32 KB: 64 cols x 256 k bf16 (W1^T), swizzled
    const int t = threadIdx.x;
    const int w = t >> 6, l = t & 63;
    const int n0 = blockIdx.x * 64;

    const int r = n0 + w * 16 + (l & 15);
    const int rc = (r < N) ? r : (N - 1);
    const int ksub = (l >> 4) * 8;
    const float* xrow = x + (size_t)rc * 256;

    // phase 1: issue ALL 16 x-loads
    float4 va[8], vb[8];
    #pragma unroll
    for (int s = 0; s < 8; ++s) {
        va[s] = *reinterpret_cast<const float4*>(xrow + s * 32 + ksub);
        vb[s] = *reinterpret_cast<const float4*>(xrow + s * 32 + ksub + 4);
    }

    // stage all of W1^T into LDS once (overlaps with x loads)
    {
        int c = t >> 2, q = t & 3;
        #pragma unroll
        for (int i = 0; i < 8; ++i) {
            int kb = q * 128 + i * 16;
            ushort8_t vv = *reinterpret_cast<const ushort8_t*>(&w1t[c * 256 + (kb >> 1)]);
            *reinterpret_cast<ushort8_t*>((char*)ldsB + SWZ_B(c, kb)) = vv;
        }
    }
    __syncthreads();

    f32x4 acc[4];
    #pragma unroll
    for (int n = 0; n < 4; ++n) acc[n] = (f32x4){0.f, 0.f, 0.f, 0.f};

    // phase 2: convert + MFMA
    #pragma unroll
    for (int s = 0; s < 8; ++s) {
        ushort8_t af;
        af[0] = f2bf(va[s].x); af[1] = f2bf(va[s].y); af[2] = f2bf(va[s].z); af[3] = f2bf(va[s].w);
        af[4] = f2bf(vb[s].x); af[5] = f2bf(vb[s].y); af[6] = f2bf(vb[s].z); af[7] = f2bf(vb[s].w);
        bf16x8 a = *reinterpret_cast<bf16x8*>(&af);
        #pragma unroll
        for (int n = 0; n < 4; ++n) {
            int c = n * 16 + (l & 15);
            bf16x8 b = *reinterpret_cast<bf16x8*>((char*)ldsB + SWZ_B(c, (s * 32 + ksub) * 2));
            acc[n] = __builtin_amdgcn_mfma_f32_16x16x32_bf16(a, b, acc[n], 0, 0, 0);
        }
    }

    // epilogue: bf16 store + per-head attention dots
    float asv[4], adv[4];
    #pragma unroll
    for (int n = 0; n < 4; ++n) {
        int c = n * 16 + (l & 15);
        asv[n] = a1_src[c];
        adv[n] = a1_dst[c];
    }
    #pragma unroll
    for (int reg = 0; reg < 4; ++reg) {
        int row = n0 + w * 16 + (l >> 4) * 4 + reg;
        bool ok = row < N;
        #pragma unroll
        for (int n = 0; n < 4; ++n) {
            float vv = acc[n][reg];
            if (ok) h1b[(size_t)row * 64 + n * 16 + (l & 15)] = f2bf(vv);
            float s = vv * asv[n];
            float d = vv * adv[n];
            s += __shfl_xor(s, 1); s += __shfl_xor(s, 2); s += __shfl_xor(s, 4);
            d += __shfl_xor(d, 1); d += __shfl_xor(d, 2); d += __shfl_xor(d, 4);
            if (ok && (l & 7) == 0) {
                int head = n * 2 + ((l & 15) >> 3);
                as1[row * 8 + head] = s;
                ad1[row * 8 + head] = d;
            }
        }
    }
}

// ---------------- phase 1: bin edges into dst-buckets ----------------
__global__ __launch_bounds__(256) void bin_kernel(const int* __restrict__ src,
                                                  const int* __restrict__ dst,
                                                  int* __restrict__ cursor,
                                                  unsigned* __restrict__ bins,
                                                  int E, int K) {
    __shared__ int hist[K_MAX];
    __shared__ int lbase[K_MAX];
    __shared__ int goff[K_MAX];
    __shared__ int rk[K_MAX];
    __shared__ int sc[256];
    __shared__ unsigned pk[CHUNK];
    __shared__ unsigned short bid[CHUNK];

    int t = threadIdx.x;
    int nchunks = (E + CHUNK - 1) / CHUNK;
    for (int c = blockIdx.x; c < nchunks; c += gridDim.x) {
        int e0 = c * CHUNK;
        int ne = E - e0; if (ne > CHUNK) ne = CHUNK;
        for (int j = t; j < K_MAX; j += 256) { hist[j] = 0; rk[j] = 0; }
        __syncthreads();

        unsigned pks[16];
        int bks[16];
        #pragma unroll
        for (int k = 0; k < 16; ++k) {
            int i = e0 + t + k * 256;
            if (i < e0 + ne) {
                int d = dst[i];
                int s = src[i];
                int b = d >> 9;
                pks[k] = ((unsigned)s << 9) | (unsigned)(d & 511);
                bks[k] = b;
                atomicAdd(&hist[b], 1);
            } else {
                bks[k] = -1;
            }
        }
        __syncthreads();
        int hv = (t < K) ? hist[t] : 0;
        int val = hv;
        sc[t] = val; __syncthreads();
        for (int off = 1; off < 256; off <<= 1) {
            int add = (t >= off) ? sc[t - off] : 0;
            __syncthreads();
            val += add; sc[t] = val;
            __syncthreads();
        }
        if (t < K) {
            lbase[t] = val - hv;
            goff[t] = hv ? atomicAdd(&cursor[t], hv) : 0;
        }
        __syncthreads();
        #pragma unroll
        for (int k = 0; k < 16; ++k) {
            if (bks[k] >= 0) {
                int r = atomicAdd(&rk[bks[k]], 1);
                int p = lbase[bks[k]] + r;
                pk[p] = pks[k];
                bid[p] = (unsigned short)bks[k];
            }
        }
        __syncthreads();
        for (int j = t; j < ne; j += 256) {
            int b = bid[j];
            bins[(size_t)b * BCAP + goff[b] + (j - lbase[b])] = pk[j];
        }
        __syncthreads();
    }
}

// ---------------- phase 2: per-bucket CSR build ----------------
__global__ __launch_bounds__(256) void csr_kernel(const unsigned* __restrict__ bins,
                                                  const int* __restrict__ cursor,
                                                  int* __restrict__ row_ptr,
                                                  int* __restrict__ csr_src,
                                                  int N, int K, int E) {
    __shared__ unsigned pk[BCAP];
    __shared__ int hist[512];
    __shared__ int ex[512];
    __shared__ int rk2[512];
    __shared__ int sc[256];
    __shared__ int bb[256];
    int b = blockIdx.x;
    int t = threadIdx.x;

    int cv = (t < K) ? cursor[t] : 0;
    int val = cv;
    sc[t] = val; __syncthreads();
    for (int off = 1; off < 256; off <<= 1) {
        int add = (t >= off) ? sc[t - off] : 0;
        __syncthreads();
        val += add; sc[t] = val;
        __syncthreads();
    }
    bb[t] = val;
    __syncthreads();
    int base_g = (b == 0) ? 0 : bb[b - 1];
    int cnt = cursor[b];
    if (b == K - 1 && t == 0) row_ptr[N] = E;
    __syncthreads();

    for (int j = t; j < cnt; j += 256) pk[j] = bins[(size_t)b * BCAP + j];
    for (int j = t; j < 512; j += 256) { hist[j] = 0; rk2[j] = 0; }
    __syncthreads();
    for (int j = t; j < cnt; j += 256) atomicAdd(&hist[pk[j] & 511u], 1);
    __syncthreads();
    int h0 = hist[2 * t], h1v = hist[2 * t + 1];
    int s = h0 + h1v;
    int v2 = s;
    sc[t] = v2; __syncthreads();
    for (int off = 1; off < 256; off <<= 1) {
        int add = (t >= off) ? sc[t - off] : 0;
        __syncthreads();
        v2 += add; sc[t] = v2;
        __syncthreads();
    }
    int excl = v2 - s;
    ex[2 * t] = excl;
    ex[2 * t + 1] = excl + h0;
    __syncthreads();
    int nd0 = b << 9;
    for (int ld = t; ld < 512; ld += 256) {
        int d = nd0 + ld;
        if (d < N) row_ptr[d] = base_g + ex[ld];
    }
    for (int j = t; j < cnt; j += 256) {
        unsigned w = pk[j];
        int ld = (int)(w & 511u);
        int r = atomicAdd(&rk2[ld], 1);
        csr_src[base_g + ex[ld] + r] = (int)(w >> 9);
    }
}

// ---------------- layer-1 gather + FUSED layer-2 GEMM ----------------
// 2 waves/block; gather: 8 lanes/edge x 8 slots; then h2 row -> LDS -> g2 = h2 @ W2
__global__ __launch_bounds__(128) void gat1_kernel(const u16* __restrict__ h1b,
                                                   const float* __restrict__ as1,
                                                   const float* __restrict__ ad1,
                                                   const int* __restrict__ row_ptr,
                                                   const int* __restrict__ csr_src,
                                                   const float* __restrict__ b1,
                                                   const float* __restrict__ W2,
                                                   const float* __restrict__ a2_src,
                                                   const float* __restrict__ a2_dst,
                                                   u16* __restrict__ g2b,
                                                   float* __restrict__ as2,
                                                   float* __restrict__ ad2, int N) {
    __shared__ float w2s[64 * 17];     // W2 padded stride 17 (bank-spread)
    __shared__ float h2s[2][64];       // per-wave h2 row
    __shared__ float a2ss[16], a2ds[16];
    const int t = threadIdx.x;
    // stage W2 + a2 vectors (all threads, before any early exit)
    for (int i = t; i < 1024; i += 128) w2s[(i >> 4) * 17 + (i & 15)] = W2[i];
    if (t < 16) { a2ss[t] = a2_src[t]; a2ds[t] = a2_dst[t]; }
    __syncthreads();

    const int wv = t >> 6;
    int dst = blockIdx.x * 2 + wv;
    if (dst >= N) return;
    int lane = t & 63;
    int slot = lane >> 3;
    int d8 = lane & 7;
    float ad = ad1[dst * 8 + d8];
    int start = row_ptr[dst], end = row_ptr[dst + 1];
    float ac0 = 0.f, ac1 = 0.f, ac2 = 0.f, ac3 = 0.f;
    float ac4 = 0.f, ac5 = 0.f, ac6 = 0.f, ac7 = 0.f;
    float ssum = 0.f;
    int i = start;
    while (i < end) {
        int nb = end - i; if (nb > 64) nb = 64;
        int sreg = (lane < nb) ? csr_src[i + lane] : 0;
        int nb16 = nb & ~15;
        int k = 0;
        for (; k < nb16; k += 16) {
            int sv0 = __shfl(sreg, k + slot);
            int sv1 = __shfl(sreg, k + 8 + slot);
            uint4 w0 = *reinterpret_cast<const uint4*>(&h1b[(size_t)sv0 * 64 + d8 * 8]);
            float av0 = as1[sv0 * 8 + d8];
            uint4 w1 = *reinterpret_cast<const uint4*>(&h1b[(size_t)sv1 * 64 + d8 * 8]);
            float av1 = as1[sv1 * 8 + d8];
            float e0 = av0 + ad; e0 = fmaxf(e0, NEG_SLOPE * e0);
            float e1 = av1 + ad; e1 = fmaxf(e1, NEG_SLOPE * e1);
            float x0 = __expf(e0);
            float x1 = __expf(e1);
            ac0 = fmaf(x0, bflo(w0.x), ac0); ac1 = fmaf(x0, bfhi(w0.x), ac1);
            ac2 = fmaf(x0, bflo(w0.y), ac2); ac3 = fmaf(x0, bfhi(w0.y), ac3);
            ac4 = fmaf(x0, bflo(w0.z), ac4); ac5 = fmaf(x0, bfhi(w0.z), ac5);
            ac6 = fmaf(x0, bflo(w0.w), ac6); ac7 = fmaf(x0, bfhi(w0.w), ac7);
            ssum += x0;
            ac0 = fmaf(x1, bflo(w1.x), ac0); ac1 = fmaf(x1, bfhi(w1.x), ac1);
            ac2 = fmaf(x1, bflo(w1.y), ac2); ac3 = fmaf(x1, bfhi(w1.y), ac3);
            ac4 = fmaf(x1, bflo(w1.z), ac4); ac5 = fmaf(x1, bfhi(w1.z), ac5);
            ac6 = fmaf(x1, bflo(w1.w), ac6); ac7 = fmaf(x1, bfhi(w1.w), ac7);
            ssum += x1;
        }
        for (; k < nb; k += 8) {
            int idx = k + slot;
            bool ok = idx < nb;
            int ridx = ok ? idx : nb - 1;
            int sv = __shfl(sreg, ridx);
            uint4 wv4 = *reinterpret_cast<const uint4*>(&h1b[(size_t)sv * 64 + d8 * 8]);
            float a = as1[sv * 8 + d8];
            float e = a + ad;
            e = fmaxf(e, NEG_SLOPE * e);
            float xx = ok ? __expf(e) : 0.f;
            ac0 = fmaf(xx, bflo(wv4.x), ac0); ac1 = fmaf(xx, bfhi(wv4.x), ac1);
            ac2 = fmaf(xx, bflo(wv4.y), ac2); ac3 = fmaf(xx, bfhi(wv4.y), ac3);
            ac4 = fmaf(xx, bflo(wv4.z), ac4); ac5 = fmaf(xx, bfhi(wv4.z), ac5);
            ac6 = fmaf(xx, bflo(wv4.w), ac6); ac7 = fmaf(xx, bfhi(wv4.w), ac7);
            ssum += xx;
        }
        i += nb;
    }
    // reduce across the 8 slots
    ac0 += __shfl_xor(ac0, 8); ac0 += __shfl_xor(ac0, 16); ac0 += __shfl_xor(ac0, 32);
    ac1 += __shfl_xor(ac1, 8); ac1 += __shfl_xor(ac1, 16); ac1 += __shfl_xor(ac1, 32);
    ac2 += __shfl_xor(ac2, 8); ac2 += __shfl_xor(ac2, 16); ac2 += __shfl_xor(ac2, 32);
    ac3 += __shfl_xor(ac3, 8); ac3 += __shfl_xor(ac3, 16); ac3 += __shfl_xor(ac3, 32);
    ac4 += __shfl_xor(ac4, 8); ac4 += __shfl_xor(ac4, 16); ac4 += __shfl_xor(ac4, 32);
    ac5 += __shfl_xor(ac5, 8); ac5 += __shfl_xor(ac5, 16); ac5 += __shfl_xor(ac5, 32);
    ac6 += __shfl_xor(ac6, 8); ac6 += __shfl_xor(ac6, 16); ac6 += __shfl_xor(ac6, 32);
    ac7 += __shfl_xor(ac7, 8); ac7 += __shfl_xor(ac7, 16); ac7 += __shfl_xor(ac7, 32);
    ssum += __shfl_xor(ssum, 8); ssum += __shfl_xor(ssum, 16); ssum += __shfl_xor(ssum, 32);
    if (slot == 0) {
        float4 bb0 = *reinterpret_cast<const float4*>(&b1[d8 * 8]);
        float4 bb1 = *reinterpret_cast<const float4*>(&b1[d8 * 8 + 4]);
        float inv = 1.f / (ssum + EPS_F);
        float o0 = ac0 * inv + bb0.x;
        float o1 = ac1 * inv + bb0.y;
        float o2 = ac2 * inv + bb0.z;
        float o3 = ac3 * inv + bb0.w;
        float o4 = ac4 * inv + bb1.x;
        float o5 = ac5 * inv + bb1.y;
        float o6 = ac6 * inv + bb1.z;
        float o7 = ac7 * inv + bb1.w;
        o0 = (o0 > 0.f) ? o0 : (__expf(o0) - 1.f);   // ELU
        o1 = (o1 > 0.f) ? o1 : (__expf(o1) - 1.f);
        o2 = (o2 > 0.f) ? o2 : (__expf(o2) - 1.f);
        o3 = (o3 > 0.f) ? o3 : (__expf(o3) - 1.f);
        o4 = (o4 > 0.f) ? o4 : (__expf(o4) - 1.f);
        o5 = (o5 > 0.f) ? o5 : (__expf(o5) - 1.f);
        o6 = (o6 > 0.f) ? o6 : (__expf(o6) - 1.f);
        o7 = (o7 > 0.f) ? o7 : (__expf(o7) - 1.f);
        *reinterpret_cast<float4*>(&h2s[wv][d8 * 8]) = make_float4(o0, o1, o2, o3);
        *reinterpret_cast<float4*>(&h2s[wv][d8 * 8 + 4]) = make_float4(o4, o5, o6, o7);
    }
    // fused layer-2 GEMM: g2[j] = sum_k h2[k] * W2[k][j]  (same-wave LDS, no barrier)
    int j = lane & 15;
    int kq = lane >> 4;
    float p = 0.f;
    #pragma unroll
    for (int kk = 0; kk < 16; ++kk) {
        int k = kq * 16 + kk;
        p = fmaf(h2s[wv][k], w2s[k * 17 + j], p);
    }
    p += __shfl_xor(p, 16);
    p += __shfl_xor(p, 32);       // all lanes: full g2[j]
    float ps = p * a2ss[j];
    float pd = p * a2ds[j];
    ps += __shfl_xor(ps, 1); ps += __shfl_xor(ps, 2); ps += __shfl_xor(ps, 4); ps += __shfl_xor(ps, 8);
    pd += __shfl_xor(pd, 1); pd += __shfl_xor(pd, 2); pd += __shfl_xor(pd, 4); pd += __shfl_xor(pd, 8);
    if (lane < 16) g2b[(size_t)dst * 16 + j] = f2bf(p);
    if (lane == 0) { as2[dst] = ps; ad2[dst] = pd; }
}

// ---------------- layer-2 gather + bias + log_softmax: 2 waves/block ----------------
__global__ __launch_bounds__(128) void gat2_kernel(const u16* __restrict__ g2b,
                                                   const float* __restrict__ as2,
                                                   const float* __restrict__ ad2,
                                                   const int* __restrict__ row_ptr,
                                                   const int* __restrict__ csr_src,
                                                   const float* __restrict__ b2,
                                                   float* __restrict__ out, int N) {
    int dst = blockIdx.x * 2 + (threadIdx.x >> 6);
    if (dst >= N) return;
    int lane = threadIdx.x & 63;
    int slot = lane >> 3, jd = lane & 7;
    float ad = ad2[dst];
    int start = row_ptr[dst], end = row_ptr[dst + 1];
    float acc0 = 0.f, acc1 = 0.f, ssum = 0.f;
    for (int base = start; base < end; base += 16) {
        #pragma unroll
        for (int g = 0; g < 2; ++g) {
            int idx = base + g * 8 + slot;
            bool ok = idx < end;
            int sidx = ok ? idx : end - 1;
            int s = csr_src[sidx];
            unsigned w = *reinterpret_cast<const unsigned*>(&g2b[(size_t)s * 16 + jd * 2]);
            float a = as2[s];
            float e = a + ad;
            e = fmaxf(e, NEG_SLOPE * e);
            float x = ok ? __expf(e) : 0.f;
            acc0 = fmaf(x, bflo(w), acc0);
            acc1 = fmaf(x, bfhi(w), acc1);
            ssum += x;
        }
    }
    acc0 += __shfl_xor(acc0, 8); acc0 += __shfl_xor(acc0, 16); acc0 += __shfl_xor(acc0, 32);
    acc1 += __shfl_xor(acc1, 8); acc1 += __shfl_xor(acc1, 16); acc1 += __shfl_xor(acc1, 32);
    ssum += __shfl_xor(ssum, 8); ssum += __shfl_xor(ssum, 16); ssum += __shfl_xor(ssum, 32);
    float inv = 1.f / (ssum + EPS_F);
    float2 bb = *reinterpret_cast<const float2*>(&b2[jd * 2]);
    float v0 = acc0 * inv + bb.x;
    float v1 = acc1 * inv + bb.y;
    float mm = fmaxf(v0, v1);
    mm = fmaxf(mm, __shfl_xor(mm, 1));
    mm = fmaxf(mm, __shfl_xor(mm, 2));
    mm = fmaxf(mm, __shfl_xor(mm, 4));
    float es = __expf(v0 - mm) + __expf(v1 - mm);
    es += __shfl_xor(es, 1); es += __shfl_xor(es, 2); es += __shfl_xor(es, 4);
    float lse = mm + __logf(es);
    if (lane < 8) {
        *reinterpret_cast<float2*>(&out[(size_t)dst * 16 + jd * 2]) = make_float2(v0, v1);
        *reinterpret_cast<float2*>(&out[(size_t)N * 16 + (size_t)dst * 16 + jd * 2]) =
            make_float2(v0 - lse, v1 - lse);
    }
}

extern "C" void kernel_launch(void* const* d_in, const int* in_sizes, int n_in,
                              void* d_out, int out_size, void* d_ws, size_t ws_size,
                              hipStream_t stream) {
    const float* x      = (const float*)d_in[0];
    const int*   eidx   = (const int*)d_in[1];
    const float* W1     = (const float*)d_in[2];
    const float* a1_src = (const float*)d_in[3];
    const float* a1_dst = (const float*)d_in[4];
    const float* b1     = (const float*)d_in[5];
    const float* W2     = (const float*)d_in[6];
    const float* a2_src = (const float*)d_in[7];
    const float* a2_dst = (const float*)d_in[8];
    const float* b2     = (const float*)d_in[9];

    const int N = in_sizes[0] / 256;
    const int E = in_sizes[1] / 2;
    const int K = (N + 511) >> 9;
    const int* esrc = eidx;
    const int* edst = eidx + E;

    char* ws = (char*)d_ws;
    size_t off = 0;
    auto alloc = [&](size_t bytes) -> void* {
        void* p = ws + off;
        off += (bytes + 255) & ~size_t(255);
        return p;
    };
    u16* h1b         = (u16*)alloc((size_t)N * 64 * 2);
    u16* w1t         = (u16*)alloc((size_t)64 * 256 * 2);
    float* as1       = (float*)alloc((size_t)N * 8 * 4);
    float* ad1       = (float*)alloc((size_t)N * 8 * 4);
    u16* g2b         = (u16*)alloc((size_t)N * 16 * 2);
    float* as2       = (float*)alloc((size_t)N * 4);
    float* ad2       = (float*)alloc((size_t)N * 4);
    int* row_ptr     = (int*)alloc((size_t)(N + 1) * 4);
    int* csr_src     = (int*)alloc((size_t)E * 4);
    int* cursor      = (int*)alloc((size_t)K_MAX * 4);
    unsigned* bins   = (unsigned*)alloc((size_t)K_MAX * BCAP * 4);

    prep_w1t_kernel<<<64, 256, 0, stream>>>(W1, w1t, cursor);
    gemm1_kernel<<<(N + 63) / 64, 256, 0, stream>>>(x, w1t, a1_src, a1_dst, h1b, as1, ad1, N);
    bin_kernel<<<(E + CHUNK - 1) / CHUNK, 256, 0, stream>>>(esrc, edst, cursor, bins, E, K);
    csr_kernel<<<K, 256, 0, stream>>>(bins, cursor, row_ptr, csr_src, N, K, E);
    gat1_kernel<<<(N + 1) / 2, 128, 0, stream>>>(h1b, as1, ad1, row_ptr, csr_src, b1,
                                                 W2, a2_src, a2_dst, g2b, as2, ad2, N);
    gat2_kernel<<<(N + 1) / 2, 128, 0, stream>>>(g2b, as2, ad2, row_ptr, csr_src, b2, (float*)d_out, N);
}

// Round 14
// 167.758 us; speedup vs baseline: 1.9795x; 1.1386x over previous
//
#include <hip/hip_runtime.h>

#define NEG_SLOPE 0.2f
#define EPS_F 1e-16f

#define K_MAX 256          // max buckets (N <= 131072)
#define BCAP 10240         // per-bucket capacity
#define CHUNK 4096         // edges per bin chunk

typedef unsigned short u16;
typedef __attribute__((ext_vector_type(8))) short bf16x8;
typedef __attribute__((ext_vector_type(4))) float f32x4;
typedef __attribute__((ext_vector_type(8))) unsigned short ushort8_t;

// round-to-nearest-even f32 -> bf16 (finite inputs)
static __device__ __forceinline__ u16 f2bf(float f) {
    unsigned u = __float_as_uint(f);
    unsigned r = (u + 0x7fffu + ((u >> 16) & 1u)) >> 16;
    return (u16)r;
}
static __device__ __forceinline__ float bflo(unsigned w) { return __uint_as_float(w << 16); }
static __device__ __forceinline__ float bfhi(unsigned w) { return __uint_as_float(w & 0xffff0000u); }

// LDS swizzle for B: XOR col-low-bits into 16B-slot bits (G4)
#define SWZ_B(c, kbyte) ((c) * 512 + ((kbyte) ^ (((c) & 7) << 4)))   // B: [64 cols][256 k] bf16

// ---------------- prep: W1 -> w1t bf16 transpose, + zero cursor ----------------
__global__ __launch_bounds__(256) void prep_w1t_kernel(const float* __restrict__ W1,
                                                       u16* __restrict__ w1t,
                                                       int* __restrict__ cursor) {
    if (blockIdx.x == 0) cursor[threadIdx.x] = 0;     // K_MAX == blockDim
    int t = blockIdx.x * 256 + threadIdx.x;   // 16384 elems
    if (t < 16384) {
        int k = t >> 6, c = t & 63;
        w1t[c * 256 + k] = f2bf(W1[t]);
    }
}

// ---------------- Layer 1 GEMM via MFMA: load-all-then-compute ----------------
__global__ __launch_bounds__(256) void gemm1_kernel(const float* __restrict__ x,
                                                    const u16* __restrict__ w1t,
                                                    const float* __restrict__ a1_src,
                                                    const float* __restrict__ a1_dst,
                                                    u16* __restrict__ h1b,
                                                    float* __restrict__ as1,
                                                    float* __restrict__ ad1, int N) {
    __shared__ u16 ldsB[16384];   // 32 KB: 64 cols x 256 k bf16 (W1^T), swizzled
    const int t = threadIdx.x;
    const int w = t >> 6, l = t & 63;
    const int n0 = blockIdx.x * 64;

    const int r = n0 + w * 16 + (l & 15);
    const int rc = (r < N) ? r : (N - 1);
    const int ksub = (l >> 4) * 8;
    const float* xrow = x + (size_t)rc * 256;

    // phase 1: issue ALL 16 x-loads
    float4 va[8], vb[8];
    #pragma unroll
    for (int s = 0; s < 8; ++s) {
        va[s] = *reinterpret_cast<const float4*>(xrow + s * 32 + ksub);
        vb[s] = *reinterpret_cast<const float4*>(xrow + s * 32 + ksub + 4);
    }

    // stage all of W1^T into LDS once (overlaps with x loads)
    {
        int c = t >> 2, q = t & 3;
        #pragma unroll
        for (int i = 0; i < 8; ++i) {
            int kb = q * 128 + i * 16;
            ushort8_t vv = *reinterpret_cast<const ushort8_t*>(&w1t[c * 256 + (kb >> 1)]);
            *reinterpret_cast<ushort8_t*>((char*)ldsB + SWZ_B(c, kb)) = vv;
        }
    }
    __syncthreads();

    f32x4 acc[4];
    #pragma unroll
    for (int n = 0; n < 4; ++n) acc[n] = (f32x4){0.f, 0.f, 0.f, 0.f};

    // phase 2: convert + MFMA
    #pragma unroll
    for (int s = 0; s < 8; ++s) {
        ushort8_t af;
        af[0] = f2bf(va[s].x); af[1] = f2bf(va[s].y); af[2] = f2bf(va[s].z); af[3] = f2bf(va[s].w);
        af[4] = f2bf(vb[s].x); af[5] = f2bf(vb[s].y); af[6] = f2bf(vb[s].z); af[7] = f2bf(vb[s].w);
        bf16x8 a = *reinterpret_cast<bf16x8*>(&af);
        #pragma unroll
        for (int n = 0; n < 4; ++n) {
            int c = n * 16 + (l & 15);
            bf16x8 b = *reinterpret_cast<bf16x8*>((char*)ldsB + SWZ_B(c, (s * 32 + ksub) * 2));
            acc[n] = __builtin_amdgcn_mfma_f32_16x16x32_bf16(a, b, acc[n], 0, 0, 0);
        }
    }

    // epilogue: bf16 store + per-head attention dots
    float asv[4], adv[4];
    #pragma unroll
    for (int n = 0; n < 4; ++n) {
        int c = n * 16 + (l & 15);
        asv[n] = a1_src[c];
        adv[n] = a1_dst[c];
    }
    #pragma unroll
    for (int reg = 0; reg < 4; ++reg) {
        int row = n0 + w * 16 + (l >> 4) * 4 + reg;
        bool ok = row < N;
        #pragma unroll
        for (int n = 0; n < 4; ++n) {
            float vv = acc[n][reg];
            if (ok) h1b[(size_t)row * 64 + n * 16 + (l & 15)] = f2bf(vv);
            float s = vv * asv[n];
            float d = vv * adv[n];
            s += __shfl_xor(s, 1); s += __shfl_xor(s, 2); s += __shfl_xor(s, 4);
            d += __shfl_xor(d, 1); d += __shfl_xor(d, 2); d += __shfl_xor(d, 4);
            if (ok && (l & 7) == 0) {
                int head = n * 2 + ((l & 15) >> 3);
                as1[row * 8 + head] = s;
                ad1[row * 8 + head] = d;
            }
        }
    }
}

// ---------------- phase 1: bin edges into dst-buckets ----------------
__global__ __launch_bounds__(256) void bin_kernel(const int* __restrict__ src,
                                                  const int* __restrict__ dst,
                                                  int* __restrict__ cursor,
                                                  unsigned* __restrict__ bins,
                                                  int E, int K) {
    __shared__ int hist[K_MAX];
    __shared__ int lbase[K_MAX];
    __shared__ int goff[K_MAX];
    __shared__ int rk[K_MAX];
    __shared__ int sc[256];
    __shared__ unsigned pk[CHUNK];
    __shared__ unsigned short bid[CHUNK];

    int t = threadIdx.x;
    int nchunks = (E + CHUNK - 1) / CHUNK;
    for (int c = blockIdx.x; c < nchunks; c += gridDim.x) {
        int e0 = c * CHUNK;
        int ne = E - e0; if (ne > CHUNK) ne = CHUNK;
        for (int j = t; j < K_MAX; j += 256) { hist[j] = 0; rk[j] = 0; }
        __syncthreads();

        unsigned pks[16];
        int bks[16];
        #pragma unroll
        for (int k = 0; k < 16; ++k) {
            int i = e0 + t + k * 256;
            if (i < e0 + ne) {
                int d = dst[i];
                int s = src[i];
                int b = d >> 9;
                pks[k] = ((unsigned)s << 9) | (unsigned)(d & 511);
                bks[k] = b;
                atomicAdd(&hist[b], 1);
            } else {
                bks[k] = -1;
            }
        }
        __syncthreads();
        int hv = (t < K) ? hist[t] : 0;
        int val = hv;
        sc[t] = val; __syncthreads();
        for (int off = 1; off < 256; off <<= 1) {
            int add = (t >= off) ? sc[t - off] : 0;
            __syncthreads();
            val += add; sc[t] = val;
            __syncthreads();
        }
        if (t < K) {
            lbase[t] = val - hv;
            goff[t] = hv ? atomicAdd(&cursor[t], hv) : 0;
        }
        __syncthreads();
        #pragma unroll
        for (int k = 0; k < 16; ++k) {
            if (bks[k] >= 0) {
                int r = atomicAdd(&rk[bks[k]], 1);
                int p = lbase[bks[k]] + r;
                pk[p] = pks[k];
                bid[p] = (unsigned short)bks[k];
            }
        }
        __syncthreads();
        for (int j = t; j < ne; j += 256) {
            int b = bid[j];
            bins[(size_t)b * BCAP + goff[b] + (j - lbase[b])] = pk[j];
        }
        __syncthreads();
    }
}

// ---------------- phase 2: per-bucket CSR build ----------------
__global__ __launch_bounds__(256) void csr_kernel(const unsigned* __restrict__ bins,
                                                  const int* __restrict__ cursor,
                                                  int* __restrict__ row_ptr,
                                                  int* __restrict__ csr_src,
                                                  int N, int K, int E) {
    __shared__ unsigned pk[BCAP];
    __shared__ int hist[512];
    __shared__ int ex[512];
    __shared__ int rk2[512];
    __shared__ int sc[256];
    __shared__ int bb[256];
    int b = blockIdx.x;
    int t = threadIdx.x;

    int cv = (t < K) ? cursor[t] : 0;
    int val = cv;
    sc[t] = val; __syncthreads();
    for (int off = 1; off < 256; off <<= 1) {
        int add = (t >= off) ? sc[t - off] : 0;
        __syncthreads();
        val += add; sc[t] = val;
        __syncthreads();
    }
    bb[t] = val;
    __syncthreads();
    int base_g = (b == 0) ? 0 : bb[b - 1];
    int cnt = cursor[b];
    if (b == K - 1 && t == 0) row_ptr[N] = E;
    __syncthreads();

    for (int j = t; j < cnt; j += 256) pk[j] = bins[(size_t)b * BCAP + j];
    for (int j = t; j < 512; j += 256) { hist[j] = 0; rk2[j] = 0; }
    __syncthreads();
    for (int j = t; j < cnt; j += 256) atomicAdd(&hist[pk[j] & 511u], 1);
    __syncthreads();
    int h0 = hist[2 * t], h1v = hist[2 * t + 1];
    int s = h0 + h1v;
    int v2 = s;
    sc[t] = v2; __syncthreads();
    for (int off = 1; off < 256; off <<= 1) {
        int add = (t >= off) ? sc[t - off] : 0;
        __syncthreads();
        v2 += add; sc[t] = v2;
        __syncthreads();
    }
    int excl = v2 - s;
    ex[2 * t] = excl;
    ex[2 * t + 1] = excl + h0;
    __syncthreads();
    int nd0 = b << 9;
    for (int ld = t; ld < 512; ld += 256) {
        int d = nd0 + ld;
        if (d < N) row_ptr[d] = base_g + ex[ld];
    }
    for (int j = t; j < cnt; j += 256) {
        unsigned w = pk[j];
        int ld = (int)(w & 511u);
        int r = atomicAdd(&rk2[ld], 1);
        csr_src[base_g + ex[ld] + r] = (int)(w >> 9);
    }
}

// ---------------- layer-1 gather: 8 lanes/edge x 8 slots, dwordx4 rows ----------------
__global__ __launch_bounds__(128) void gat1_kernel(const u16* __restrict__ h1b,
                                                   const float* __restrict__ as1,
                                                   const float* __restrict__ ad1,
                                                   const int* __restrict__ row_ptr,
                                                   const int* __restrict__ csr_src,
                                                   const float* __restrict__ b1,
                                                   float* __restrict__ h2, int N) {
    int dst = blockIdx.x * 2 + (threadIdx.x >> 6);
    if (dst >= N) return;
    int lane = threadIdx.x & 63;
    int slot = lane >> 3;
    int d8 = lane & 7;
    float ad = ad1[dst * 8 + d8];
    int start = row_ptr[dst], end = row_ptr[dst + 1];
    float ac0 = 0.f, ac1 = 0.f, ac2 = 0.f, ac3 = 0.f;
    float ac4 = 0.f, ac5 = 0.f, ac6 = 0.f, ac7 = 0.f;
    float ssum = 0.f;
    int i = start;
    while (i < end) {
        int nb = end - i; if (nb > 64) nb = 64;
        int sreg = (lane < nb) ? csr_src[i + lane] : 0;
        int nb16 = nb & ~15;
        int k = 0;
        for (; k < nb16; k += 16) {
            int sv0 = __shfl(sreg, k + slot);
            int sv1 = __shfl(sreg, k + 8 + slot);
            uint4 w0 = *reinterpret_cast<const uint4*>(&h1b[(size_t)sv0 * 64 + d8 * 8]);
            float av0 = as1[sv0 * 8 + d8];
            uint4 w1 = *reinterpret_cast<const uint4*>(&h1b[(size_t)sv1 * 64 + d8 * 8]);
            float av1 = as1[sv1 * 8 + d8];
            float e0 = av0 + ad; e0 = fmaxf(e0, NEG_SLOPE * e0);
            float e1 = av1 + ad; e1 = fmaxf(e1, NEG_SLOPE * e1);
            float x0 = __expf(e0);
            float x1 = __expf(e1);
            ac0 = fmaf(x0, bflo(w0.x), ac0); ac1 = fmaf(x0, bfhi(w0.x), ac1);
            ac2 = fmaf(x0, bflo(w0.y), ac2); ac3 = fmaf(x0, bfhi(w0.y), ac3);
            ac4 = fmaf(x0, bflo(w0.z), ac4); ac5 = fmaf(x0, bfhi(w0.z), ac5);
            ac6 = fmaf(x0, bflo(w0.w), ac6); ac7 = fmaf(x0, bfhi(w0.w), ac7);
            ssum += x0;
            ac0 = fmaf(x1, bflo(w1.x), ac0); ac1 = fmaf(x1, bfhi(w1.x), ac1);
            ac2 = fmaf(x1, bflo(w1.y), ac2); ac3 = fmaf(x1, bfhi(w1.y), ac3);
            ac4 = fmaf(x1, bflo(w1.z), ac4); ac5 = fmaf(x1, bfhi(w1.z), ac5);
            ac6 = fmaf(x1, bflo(w1.w), ac6); ac7 = fmaf(x1, bfhi(w1.w), ac7);
            ssum += x1;
        }
        for (; k < nb; k += 8) {
            int idx = k + slot;
            bool ok = idx < nb;
            int ridx = ok ? idx : nb - 1;
            int sv = __shfl(sreg, ridx);
            uint4 wv = *reinterpret_cast<const uint4*>(&h1b[(size_t)sv * 64 + d8 * 8]);
            float a = as1[sv * 8 + d8];
            float e = a + ad;
            e = fmaxf(e, NEG_SLOPE * e);
            float xx = ok ? __expf(e) : 0.f;
            ac0 = fmaf(xx, bflo(wv.x), ac0); ac1 = fmaf(xx, bfhi(wv.x), ac1);
            ac2 = fmaf(xx, bflo(wv.y), ac2); ac3 = fmaf(xx, bfhi(wv.y), ac3);
            ac4 = fmaf(xx, bflo(wv.z), ac4); ac5 = fmaf(xx, bfhi(wv.z), ac5);
            ac6 = fmaf(xx, bflo(wv.w), ac6); ac7 = fmaf(xx, bfhi(wv.w), ac7);
            ssum += xx;
        }
        i += nb;
    }
    // reduce across the 8 slots (lane bits 3,4,5)
    ac0 += __shfl_xor(ac0, 8); ac0 += __shfl_xor(ac0, 16); ac0 += __shfl_xor(ac0, 32);
    ac1 += __shfl_xor(ac1, 8); ac1 += __shfl_xor(ac1, 16); ac1 += __shfl_xor(ac1, 32);
    ac2 += __shfl_xor(ac2, 8); ac2 += __shfl_xor(ac2, 16); ac2 += __shfl_xor(ac2, 32);
    ac3 += __shfl_xor(ac3, 8); ac3 += __shfl_xor(ac3, 16); ac3 += __shfl_xor(ac3, 32);
    ac4 += __shfl_xor(ac4, 8); ac4 += __shfl_xor(ac4, 16); ac4 += __shfl_xor(ac4, 32);
    ac5 += __shfl_xor(ac5, 8); ac5 += __shfl_xor(ac5, 16); ac5 += __shfl_xor(ac5, 32);
    ac6 += __shfl_xor(ac6, 8); ac6 += __shfl_xor(ac6, 16); ac6 += __shfl_xor(ac6, 32);
    ac7 += __shfl_xor(ac7, 8); ac7 += __shfl_xor(ac7, 16); ac7 += __shfl_xor(ac7, 32);
    ssum += __shfl_xor(ssum, 8); ssum += __shfl_xor(ssum, 16); ssum += __shfl_xor(ssum, 32);
    if (slot == 0) {
        float4 bb0 = *reinterpret_cast<const float4*>(&b1[d8 * 8]);
        float4 bb1 = *reinterpret_cast<const float4*>(&b1[d8 * 8 + 4]);
        float inv = 1.f / (ssum + EPS_F);
        float o0 = ac0 * inv + bb0.x;
        float o1 = ac1 * inv + bb0.y;
        float o2 = ac2 * inv + bb0.z;
        float o3 = ac3 * inv + bb0.w;
        float o4 = ac4 * inv + bb1.x;
        float o5 = ac5 * inv + bb1.y;
        float o6 = ac6 * inv + bb1.z;
        float o7 = ac7 * inv + bb1.w;
        o0 = (o0 > 0.f) ? o0 : (__expf(o0) - 1.f);   // ELU
        o1 = (o1 > 0.f) ? o1 : (__expf(o1) - 1.f);
        o2 = (o2 > 0.f) ? o2 : (__expf(o2) - 1.f);
        o3 = (o3 > 0.f) ? o3 : (__expf(o3) - 1.f);
        o4 = (o4 > 0.f) ? o4 : (__expf(o4) - 1.f);
        o5 = (o5 > 0.f) ? o5 : (__expf(o5) - 1.f);
        o6 = (o6 > 0.f) ? o6 : (__expf(o6) - 1.f);
        o7 = (o7 > 0.f) ? o7 : (__expf(o7) - 1.f);
        *reinterpret_cast<float4*>(&h2[(size_t)dst * 64 + d8 * 8]) = make_float4(o0, o1, o2, o3);
        *reinterpret_cast<float4*>(&h2[(size_t)dst * 64 + d8 * 8 + 4]) = make_float4(o4, o5, o6, o7);
    }
}

// ---------------- Layer 2 GEMM: g2b = bf16(h2 @ W2), + src/dst dots ----------------
__global__ __launch_bounds__(256) void gemm2_kernel(const float* __restrict__ h2,
                                                    const float* __restrict__ W2,
                                                    const float* __restrict__ a2_src,
                                                    const float* __restrict__ a2_dst,
                                                    u16* __restrict__ g2b,
                                                    float* __restrict__ as2,
                                                    float* __restrict__ ad2, int N) {
    __shared__ float hs[64][68];
    __shared__ float ws[1024];
    int t = threadIdx.x;
    int n0 = blockIdx.x * 64;
    *reinterpret_cast<float4*>(&ws[t * 4]) = *reinterpret_cast<const float4*>(&W2[t * 4]);
    #pragma unroll
    for (int ii = 0; ii < 4; ++ii) {
        int fidx = (ii * 256 + t) * 4;
        int row = fidx >> 6;
        int col = fidx & 63;
        float4 v = make_float4(0.f, 0.f, 0.f, 0.f);
        if (n0 + row < N) v = *reinterpret_cast<const float4*>(&h2[(size_t)(n0 + row) * 64 + col]);
        *reinterpret_cast<float4*>(&hs[row][col]) = v;
    }
    __syncthreads();
    int node = t >> 2, j4 = t & 3;
    float4 acc = make_float4(0.f, 0.f, 0.f, 0.f);
    #pragma unroll
    for (int k = 0; k < 64; ++k) {
        float hk = hs[node][k];
        float4 w = *reinterpret_cast<const float4*>(&ws[k * 16 + j4 * 4]);
        acc.x = fmaf(hk, w.x, acc.x);
        acc.y = fmaf(hk, w.y, acc.y);
        acc.z = fmaf(hk, w.z, acc.z);
        acc.w = fmaf(hk, w.w, acc.w);
    }
    float4 asv = *reinterpret_cast<const float4*>(&a2_src[j4 * 4]);
    float4 adv = *reinterpret_cast<const float4*>(&a2_dst[j4 * 4]);
    float ps = acc.x * asv.x + acc.y * asv.y + acc.z * asv.z + acc.w * asv.w;
    float pd = acc.x * adv.x + acc.y * adv.y + acc.z * adv.z + acc.w * adv.w;
    ps += __shfl_xor(ps, 1); ps += __shfl_xor(ps, 2);
    pd += __shfl_xor(pd, 1); pd += __shfl_xor(pd, 2);
    int gnode = n0 + node;
    if (gnode < N) {
        ushort4 p;
        p.x = f2bf(acc.x); p.y = f2bf(acc.y);
        p.z = f2bf(acc.z); p.w = f2bf(acc.w);
        *reinterpret_cast<ushort4*>(&g2b[(size_t)gnode * 16 + j4 * 4]) = p;
        if (j4 == 0) { as2[gnode] = ps; ad2[gnode] = pd; }
    }
}

// ---------------- layer-2 gather + bias + log_softmax: 2 waves/block ----------------
__global__ __launch_bounds__(128) void gat2_kernel(const u16* __restrict__ g2b,
                                                   const float* __restrict__ as2,
                                                   const float* __restrict__ ad2,
                                                   const int* __restrict__ row_ptr,
                                                   const int* __restrict__ csr_src,
                                                   const float* __restrict__ b2,
                                                   float* __restrict__ out, int N) {
    int dst = blockIdx.x * 2 + (threadIdx.x >> 6);
    if (dst >= N) return;
    int lane = threadIdx.x & 63;
    int slot = lane >> 3, jd = lane & 7;
    float ad = ad2[dst];
    int start = row_ptr[dst], end = row_ptr[dst + 1];
    float acc0 = 0.f, acc1 = 0.f, ssum = 0.f;
    for (int base = start; base < end; base += 16) {
        #pragma unroll
        for (int g = 0; g < 2; ++g) {
            int idx = base + g * 8 + slot;
            bool ok = idx < end;
            int sidx = ok ? idx : end - 1;
            int s = csr_src[sidx];
            unsigned w = *reinterpret_cast<const unsigned*>(&g2b[(size_t)s * 16 + jd * 2]);
            float a = as2[s];
            float e = a + ad;
            e = fmaxf(e, NEG_SLOPE * e);
            float x = ok ? __expf(e) : 0.f;
            acc0 = fmaf(x, bflo(w), acc0);
            acc1 = fmaf(x, bfhi(w), acc1);
            ssum += x;
        }
    }
    acc0 += __shfl_xor(acc0, 8); acc0 += __shfl_xor(acc0, 16); acc0 += __shfl_xor(acc0, 32);
    acc1 += __shfl_xor(acc1, 8); acc1 += __shfl_xor(acc1, 16); acc1 += __shfl_xor(acc1, 32);
    ssum += __shfl_xor(ssum, 8); ssum += __shfl_xor(ssum, 16); ssum += __shfl_xor(ssum, 32);
    float inv = 1.f / (ssum + EPS_F);
    float2 bb = *reinterpret_cast<const float2*>(&b2[jd * 2]);
    float v0 = acc0 * inv + bb.x;
    float v1 = acc1 * inv + bb.y;
    float mm = fmaxf(v0, v1);
    mm = fmaxf(mm, __shfl_xor(mm, 1));
    mm = fmaxf(mm, __shfl_xor(mm, 2));
    mm = fmaxf(mm, __shfl_xor(mm, 4));
    float es = __expf(v0 - mm) + __expf(v1 - mm);
    es += __shfl_xor(es, 1); es += __shfl_xor(es, 2); es += __shfl_xor(es, 4);
    float lse = mm + __logf(es);
    if (lane < 8) {
        *reinterpret_cast<float2*>(&out[(size_t)dst * 16 + jd * 2]) = make_float2(v0, v1);
        *reinterpret_cast<float2*>(&out[(size_t)N * 16 + (size_t)dst * 16 + jd * 2]) =
            make_float2(v0 - lse, v1 - lse);
    }
}

extern "C" void kernel_launch(void* const* d_in, const int* in_sizes, int n_in,
                              void* d_out, int out_size, void* d_ws, size_t ws_size,
                              hipStream_t stream) {
    const float* x      = (const float*)d_in[0];
    const int*   eidx   = (const int*)d_in[1];
    const float* W1     = (const float*)d_in[2];
    const float* a1_src = (const float*)d_in[3];
    const float* a1_dst = (const float*)d_in[4];
    const float* b1     = (const float*)d_in[5];
    const float* W2     = (const float*)d_in[6];
    const float* a2_src = (const float*)d_in[7];
    const float* a2_dst = (const float*)d_in[8];
    const float* b2     = (const float*)d_in[9];

    const int N = in_sizes[0] / 256;
    const int E = in_sizes[1] / 2;
    const int K = (N + 511) >> 9;
    const int* esrc = eidx;
    const int* edst = eidx + E;

    char* ws = (char*)d_ws;
    size_t off = 0;
    auto alloc = [&](size_t bytes) -> void* {
        void* p = ws + off;
        off += (bytes + 255) & ~size_t(255);
        return p;
    };
    u16* h1b         = (u16*)alloc((size_t)N * 64 * 2);
    u16* w1t         = (u16*)alloc((size_t)64 * 256 * 2);
    float* as1       = (float*)alloc((size_t)N * 8 * 4);
    float* ad1       = (float*)alloc((size_t)N * 8 * 4);
    float* h2        = (float*)alloc((size_t)N * 64 * 4);
    u16* g2b         = (u16*)alloc((size_t)N * 16 * 2);
    float* as2       = (float*)alloc((size_t)N * 4);
    float* ad2       = (float*)alloc((size_t)N * 4);
    int* row_ptr     = (int*)alloc((size_t)(N + 1) * 4);
    int* csr_src     = (int*)alloc((size_t)E * 4);
    int* cursor      = (int*)alloc((size_t)K_MAX * 4);
    unsigned* bins   = (unsigned*)alloc((size_t)K_MAX * BCAP * 4);

    prep_w1t_kernel<<<64, 256, 0, stream>>>(W1, w1t, cursor);
    gemm1_kernel<<<(N + 63) / 64, 256, 0, stream>>>(x, w1t, a1_src, a1_dst, h1b, as1, ad1, N);
    bin_kernel<<<(E + CHUNK - 1) / CHUNK, 256, 0, stream>>>(esrc, edst, cursor, bins, E, K);
    csr_kernel<<<K, 256, 0, stream>>>(bins, cursor, row_ptr, csr_src, N, K, E);
    gat1_kernel<<<(N + 1) / 2, 128, 0, stream>>>(h1b, as1, ad1, row_ptr, csr_src, b1, h2, N);
    gemm2_kernel<<<(N + 63) / 64, 256, 0, stream>>>(h2, W2, a2_src, a2_dst, g2b, as2, ad2, N);
    gat2_kernel<<<(N + 1) / 2, 128, 0, stream>>>(g2b, as2, ad2, row_ptr, csr_src, b2, (float*)d_out, N);
}

// Round 15
// 162.518 us; speedup vs baseline: 2.0433x; 1.0322x over previous
//
#include <hip/hip_runtime.h>

#define NEG_SLOPE 0.2f
#define EPS_F 1e-16f

#define K_MAX 256          // max buckets (N <= 131072)
#define BCAP 10240         // per-bucket capacity
#define CHUNK 4096         // edges per bin chunk

typedef unsigned short u16;
typedef __attribute__((ext_vector_type(8))) short bf16x8;
typedef __attribute__((ext_vector_type(4))) float f32x4;
typedef __attribute__((ext_vector_type(8))) unsigned short ushort8_t;

// round-to-nearest-even f32 -> bf16 (finite inputs)
static __device__ __forceinline__ u16 f2bf(float f) {
    unsigned u = __float_as_uint(f);
    unsigned r = (u + 0x7fffu + ((u >> 16) & 1u)) >> 16;
    return (u16)r;
}
static __device__ __forceinline__ float bflo(unsigned w) { return __uint_as_float(w << 16); }
static __device__ __forceinline__ float bfhi(unsigned w) { return __uint_as_float(w & 0xffff0000u); }

// LDS swizzle for B: XOR col-low-bits into 16B-slot bits (G4)
#define SWZ_B(c, kbyte) ((c) * 512 + ((kbyte) ^ (((c) & 7) << 4)))   // B: [64 cols][256 k] bf16

// ---------------- prep: W1 -> w1t bf16 transpose, + zero cursor ----------------
__global__ __launch_bounds__(256) void prep_w1t_kernel(const float* __restrict__ W1,
                                                       u16* __restrict__ w1t,
                                                       int* __restrict__ cursor) {
    if (blockIdx.x == 0) cursor[threadIdx.x] = 0;     // K_MAX == blockDim
    int t = blockIdx.x * 256 + threadIdx.x;   // 16384 elems
    if (t < 16384) {
        int k = t >> 6, c = t & 63;
        w1t[c * 256 + k] = f2bf(W1[t]);
    }
}

// ---------------- FRONT: blocks [0,G1) = Layer-1 GEMM, blocks [G1,G1+GB) = edge binning ----
__global__ __launch_bounds__(256) void front_kernel(const float* __restrict__ x,
                                                    const u16* __restrict__ w1t,
                                                    const float* __restrict__ a1_src,
                                                    const float* __restrict__ a1_dst,
                                                    u16* __restrict__ h1b,
                                                    float* __restrict__ as1,
                                                    float* __restrict__ ad1, int N,
                                                    const int* __restrict__ esrc,
                                                    const int* __restrict__ edst,
                                                    int* __restrict__ cursor,
                                                    unsigned* __restrict__ bins,
                                                    int E, int K, int G1, int GB) {
    __shared__ char lds_raw[32768];
    const int t = threadIdx.x;

    if ((int)blockIdx.x < G1) {
        // ---------------- gemm1 branch ----------------
        u16* ldsB = (u16*)lds_raw;    // 32 KB: 64 cols x 256 k bf16 (W1^T), swizzled
        const int w = t >> 6, l = t & 63;
        const int n0 = blockIdx.x * 64;

        const int r = n0 + w * 16 + (l & 15);
        const int rc = (r < N) ? r : (N - 1);
        const int ksub = (l >> 4) * 8;
        const float* xrow = x + (size_t)rc * 256;

        // phase 1: issue ALL 16 x-loads
        float4 va[8], vb[8];
        #pragma unroll
        for (int s = 0; s < 8; ++s) {
            va[s] = *reinterpret_cast<const float4*>(xrow + s * 32 + ksub);
            vb[s] = *reinterpret_cast<const float4*>(xrow + s * 32 + ksub + 4);
        }

        // stage W1^T into LDS (overlaps with x loads)
        {
            int c = t >> 2, q = t & 3;
            #pragma unroll
            for (int i = 0; i < 8; ++i) {
                int kb = q * 128 + i * 16;
                ushort8_t vv = *reinterpret_cast<const ushort8_t*>(&w1t[c * 256 + (kb >> 1)]);
                *reinterpret_cast<ushort8_t*>((char*)ldsB + SWZ_B(c, kb)) = vv;
            }
        }
        __syncthreads();

        f32x4 acc[4];
        #pragma unroll
        for (int n = 0; n < 4; ++n) acc[n] = (f32x4){0.f, 0.f, 0.f, 0.f};

        #pragma unroll
        for (int s = 0; s < 8; ++s) {
            ushort8_t af;
            af[0] = f2bf(va[s].x); af[1] = f2bf(va[s].y); af[2] = f2bf(va[s].z); af[3] = f2bf(va[s].w);
            af[4] = f2bf(vb[s].x); af[5] = f2bf(vb[s].y); af[6] = f2bf(vb[s].z); af[7] = f2bf(vb[s].w);
            bf16x8 a = *reinterpret_cast<bf16x8*>(&af);
            #pragma unroll
            for (int n = 0; n < 4; ++n) {
                int c = n * 16 + (l & 15);
                bf16x8 b = *reinterpret_cast<bf16x8*>((char*)ldsB + SWZ_B(c, (s * 32 + ksub) * 2));
                acc[n] = __builtin_amdgcn_mfma_f32_16x16x32_bf16(a, b, acc[n], 0, 0, 0);
            }
        }

        float asv[4], adv[4];
        #pragma unroll
        for (int n = 0; n < 4; ++n) {
            int c = n * 16 + (l & 15);
            asv[n] = a1_src[c];
            adv[n] = a1_dst[c];
        }
        #pragma unroll
        for (int reg = 0; reg < 4; ++reg) {
            int row = n0 + w * 16 + (l >> 4) * 4 + reg;
            bool ok = row < N;
            #pragma unroll
            for (int n = 0; n < 4; ++n) {
                float vv = acc[n][reg];
                if (ok) h1b[(size_t)row * 64 + n * 16 + (l & 15)] = f2bf(vv);
                float s = vv * asv[n];
                float d = vv * adv[n];
                s += __shfl_xor(s, 1); s += __shfl_xor(s, 2); s += __shfl_xor(s, 4);
                d += __shfl_xor(d, 1); d += __shfl_xor(d, 2); d += __shfl_xor(d, 4);
                if (ok && (l & 7) == 0) {
                    int head = n * 2 + ((l & 15) >> 3);
                    as1[row * 8 + head] = s;
                    ad1[row * 8 + head] = d;
                }
            }
        }
    } else {
        // ---------------- bin branch ----------------
        int* hist   = (int*)lds_raw;              // 256
        int* lbase  = hist + 256;                 // 256
        int* goff   = lbase + 256;                // 256
        int* rk     = goff + 256;                 // 256
        int* sc     = rk + 256;                   // 256  (5 KB so far)
        unsigned short* bid = (unsigned short*)(sc + 256);   // 4096 u16 (8 KB)
        unsigned* pk = (unsigned*)(bid + CHUNK);             // 4096 u32 (16 KB) -> 29 KB total

        int nchunks = (E + CHUNK - 1) / CHUNK;
        for (int c = blockIdx.x - G1; c < nchunks; c += GB) {
            int e0 = c * CHUNK;
            int ne = E - e0; if (ne > CHUNK) ne = CHUNK;
            for (int j = t; j < K_MAX; j += 256) { hist[j] = 0; rk[j] = 0; }
            __syncthreads();

            unsigned pks[16];
            int bks[16];
            #pragma unroll
            for (int k = 0; k < 16; ++k) {
                int i = e0 + t + k * 256;
                if (i < e0 + ne) {
                    int d = edst[i];
                    int s = esrc[i];
                    int b = d >> 9;
                    pks[k] = ((unsigned)s << 9) | (unsigned)(d & 511);
                    bks[k] = b;
                    atomicAdd(&hist[b], 1);
                } else {
                    bks[k] = -1;
                }
            }
            __syncthreads();
            int hv = (t < K) ? hist[t] : 0;
            int val = hv;
            sc[t] = val; __syncthreads();
            for (int off = 1; off < 256; off <<= 1) {
                int add = (t >= off) ? sc[t - off] : 0;
                __syncthreads();
                val += add; sc[t] = val;
                __syncthreads();
            }
            if (t < K) {
                lbase[t] = val - hv;
                goff[t] = hv ? atomicAdd(&cursor[t], hv) : 0;
            }
            __syncthreads();
            #pragma unroll
            for (int k = 0; k < 16; ++k) {
                if (bks[k] >= 0) {
                    int r = atomicAdd(&rk[bks[k]], 1);
                    int p = lbase[bks[k]] + r;
                    pk[p] = pks[k];
                    bid[p] = (unsigned short)bks[k];
                }
            }
            __syncthreads();
            for (int j = t; j < ne; j += 256) {
                int b = bid[j];
                bins[(size_t)b * BCAP + goff[b] + (j - lbase[b])] = pk[j];
            }
            __syncthreads();
        }
    }
}

// ---------------- phase 2: per-bucket CSR build ----------------
__global__ __launch_bounds__(256) void csr_kernel(const unsigned* __restrict__ bins,
                                                  const int* __restrict__ cursor,
                                                  int* __restrict__ row_ptr,
                                                  int* __restrict__ csr_src,
                                                  int N, int K, int E) {
    __shared__ unsigned pk[BCAP];
    __shared__ int hist[512];
    __shared__ int ex[512];
    __shared__ int rk2[512];
    __shared__ int sc[256];
    __shared__ int bb[256];
    int b = blockIdx.x;
    int t = threadIdx.x;

    int cv = (t < K) ? cursor[t] : 0;
    int val = cv;
    sc[t] = val; __syncthreads();
    for (int off = 1; off < 256; off <<= 1) {
        int add = (t >= off) ? sc[t - off] : 0;
        __syncthreads();
        val += add; sc[t] = val;
        __syncthreads();
    }
    bb[t] = val;
    __syncthreads();
    int base_g = (b == 0) ? 0 : bb[b - 1];
    int cnt = cursor[b];
    if (b == K - 1 && t == 0) row_ptr[N] = E;
    __syncthreads();

    for (int j = t; j < cnt; j += 256) pk[j] = bins[(size_t)b * BCAP + j];
    for (int j = t; j < 512; j += 256) { hist[j] = 0; rk2[j] = 0; }
    __syncthreads();
    for (int j = t; j < cnt; j += 256) atomicAdd(&hist[pk[j] & 511u], 1);
    __syncthreads();
    int h0 = hist[2 * t], h1v = hist[2 * t + 1];
    int s = h0 + h1v;
    int v2 = s;
    sc[t] = v2; __syncthreads();
    for (int off = 1; off < 256; off <<= 1) {
        int add = (t >= off) ? sc[t - off] : 0;
        __syncthreads();
        v2 += add; sc[t] = v2;
        __syncthreads();
    }
    int excl = v2 - s;
    ex[2 * t] = excl;
    ex[2 * t + 1] = excl + h0;
    __syncthreads();
    int nd0 = b << 9;
    for (int ld = t; ld < 512; ld += 256) {
        int d = nd0 + ld;
        if (d < N) row_ptr[d] = base_g + ex[ld];
    }
    for (int j = t; j < cnt; j += 256) {
        unsigned w = pk[j];
        int ld = (int)(w & 511u);
        int r = atomicAdd(&rk2[ld], 1);
        csr_src[base_g + ex[ld] + r] = (int)(w >> 9);
    }
}

// ---------------- layer-1 gather: 8 lanes/edge x 8 slots, dwordx4 rows ----------------
__global__ __launch_bounds__(128) void gat1_kernel(const u16* __restrict__ h1b,
                                                   const float* __restrict__ as1,
                                                   const float* __restrict__ ad1,
                                                   const int* __restrict__ row_ptr,
                                                   const int* __restrict__ csr_src,
                                                   const float* __restrict__ b1,
                                                   float* __restrict__ h2, int N) {
    int dst = blockIdx.x * 2 + (threadIdx.x >> 6);
    if (dst >= N) return;
    int lane = threadIdx.x & 63;
    int slot = lane >> 3;
    int d8 = lane & 7;
    float ad = ad1[dst * 8 + d8];
    int start = row_ptr[dst], end = row_ptr[dst + 1];
    float ac0 = 0.f, ac1 = 0.f, ac2 = 0.f, ac3 = 0.f;
    float ac4 = 0.f, ac5 = 0.f, ac6 = 0.f, ac7 = 0.f;
    float ssum = 0.f;
    int i = start;
    while (i < end) {
        int nb = end - i; if (nb > 64) nb = 64;
        int sreg = (lane < nb) ? csr_src[i + lane] : 0;
        int nb16 = nb & ~15;
        int k = 0;
        for (; k < nb16; k += 16) {
            int sv0 = __shfl(sreg, k + slot);
            int sv1 = __shfl(sreg, k + 8 + slot);
            uint4 w0 = *reinterpret_cast<const uint4*>(&h1b[(size_t)sv0 * 64 + d8 * 8]);
            float av0 = as1[sv0 * 8 + d8];
            uint4 w1 = *reinterpret_cast<const uint4*>(&h1b[(size_t)sv1 * 64 + d8 * 8]);
            float av1 = as1[sv1 * 8 + d8];
            float e0 = av0 + ad; e0 = fmaxf(e0, NEG_SLOPE * e0);
            float e1 = av1 + ad; e1 = fmaxf(e1, NEG_SLOPE * e1);
            float x0 = __expf(e0);
            float x1 = __expf(e1);
            ac0 = fmaf(x0, bflo(w0.x), ac0); ac1 = fmaf(x0, bfhi(w0.x), ac1);
            ac2 = fmaf(x0, bflo(w0.y), ac2); ac3 = fmaf(x0, bfhi(w0.y), ac3);
            ac4 = fmaf(x0, bflo(w0.z), ac4); ac5 = fmaf(x0, bfhi(w0.z), ac5);
            ac6 = fmaf(x0, bflo(w0.w), ac6); ac7 = fmaf(x0, bfhi(w0.w), ac7);
            ssum += x0;
            ac0 = fmaf(x1, bflo(w1.x), ac0); ac1 = fmaf(x1, bfhi(w1.x), ac1);
            ac2 = fmaf(x1, bflo(w1.y), ac2); ac3 = fmaf(x1, bfhi(w1.y), ac3);
            ac4 = fmaf(x1, bflo(w1.z), ac4); ac5 = fmaf(x1, bfhi(w1.z), ac5);
            ac6 = fmaf(x1, bflo(w1.w), ac6); ac7 = fmaf(x1, bfhi(w1.w), ac7);
            ssum += x1;
        }
        for (; k < nb; k += 8) {
            int idx = k + slot;
            bool ok = idx < nb;
            int ridx = ok ? idx : nb - 1;
            int sv = __shfl(sreg, ridx);
            uint4 wv = *reinterpret_cast<const uint4*>(&h1b[(size_t)sv * 64 + d8 * 8]);
            float a = as1[sv * 8 + d8];
            float e = a + ad;
            e = fmaxf(e, NEG_SLOPE * e);
            float xx = ok ? __expf(e) : 0.f;
            ac0 = fmaf(xx, bflo(wv.x), ac0); ac1 = fmaf(xx, bfhi(wv.x), ac1);
            ac2 = fmaf(xx, bflo(wv.y), ac2); ac3 = fmaf(xx, bfhi(wv.y), ac3);
            ac4 = fmaf(xx, bflo(wv.z), ac4); ac5 = fmaf(xx, bfhi(wv.z), ac5);
            ac6 = fmaf(xx, bflo(wv.w), ac6); ac7 = fmaf(xx, bfhi(wv.w), ac7);
            ssum += xx;
        }
        i += nb;
    }
    ac0 += __shfl_xor(ac0, 8); ac0 += __shfl_xor(ac0, 16); ac0 += __shfl_xor(ac0, 32);
    ac1 += __shfl_xor(ac1, 8); ac1 += __shfl_xor(ac1, 16); ac1 += __shfl_xor(ac1, 32);
    ac2 += __shfl_xor(ac2, 8); ac2 += __shfl_xor(ac2, 16); ac2 += __shfl_xor(ac2, 32);
    ac3 += __shfl_xor(ac3, 8); ac3 += __shfl_xor(ac3, 16); ac3 += __shfl_xor(ac3, 32);
    ac4 += __shfl_xor(ac4, 8); ac4 += __shfl_xor(ac4, 16); ac4 += __shfl_xor(ac4, 32);
    ac5 += __shfl_xor(ac5, 8); ac5 += __shfl_xor(ac5, 16); ac5 += __shfl_xor(ac5, 32);
    ac6 += __shfl_xor(ac6, 8); ac6 += __shfl_xor(ac6, 16); ac6 += __shfl_xor(ac6, 32);
    ac7 += __shfl_xor(ac7, 8); ac7 += __shfl_xor(ac7, 16); ac7 += __shfl_xor(ac7, 32);
    ssum += __shfl_xor(ssum, 8); ssum += __shfl_xor(ssum, 16); ssum += __shfl_xor(ssum, 32);
    if (slot == 0) {
        float4 bb0 = *reinterpret_cast<const float4*>(&b1[d8 * 8]);
        float4 bb1 = *reinterpret_cast<const float4*>(&b1[d8 * 8 + 4]);
        float inv = 1.f / (ssum + EPS_F);
        float o0 = ac0 * inv + bb0.x;
        float o1 = ac1 * inv + bb0.y;
        float o2 = ac2 * inv + bb0.z;
        float o3 = ac3 * inv + bb0.w;
        float o4 = ac4 * inv + bb1.x;
        float o5 = ac5 * inv + bb1.y;
        float o6 = ac6 * inv + bb1.z;
        float o7 = ac7 * inv + bb1.w;
        o0 = (o0 > 0.f) ? o0 : (__expf(o0) - 1.f);   // ELU
        o1 = (o1 > 0.f) ? o1 : (__expf(o1) - 1.f);
        o2 = (o2 > 0.f) ? o2 : (__expf(o2) - 1.f);
        o3 = (o3 > 0.f) ? o3 : (__expf(o3) - 1.f);
        o4 = (o4 > 0.f) ? o4 : (__expf(o4) - 1.f);
        o5 = (o5 > 0.f) ? o5 : (__expf(o5) - 1.f);
        o6 = (o6 > 0.f) ? o6 : (__expf(o6) - 1.f);
        o7 = (o7 > 0.f) ? o7 : (__expf(o7) - 1.f);
        *reinterpret_cast<float4*>(&h2[(size_t)dst * 64 + d8 * 8]) = make_float4(o0, o1, o2, o3);
        *reinterpret_cast<float4*>(&h2[(size_t)dst * 64 + d8 * 8 + 4]) = make_float4(o4, o5, o6, o7);
    }
}

// ---------------- Layer 2 GEMM: g2b = bf16(h2 @ W2), + src/dst dots ----------------
__global__ __launch_bounds__(256) void gemm2_kernel(const float* __restrict__ h2,
                                                    const float* __restrict__ W2,
                                                    const float* __restrict__ a2_src,
                                                    const float* __restrict__ a2_dst,
                                                    u16* __restrict__ g2b,
                                                    float* __restrict__ as2,
                                                    float* __restrict__ ad2, int N) {
    __shared__ float hs[64][68];
    __shared__ float ws[1024];
    int t = threadIdx.x;
    int n0 = blockIdx.x * 64;
    *reinterpret_cast<float4*>(&ws[t * 4]) = *reinterpret_cast<const float4*>(&W2[t * 4]);
    #pragma unroll
    for (int ii = 0; ii < 4; ++ii) {
        int fidx = (ii * 256 + t) * 4;
        int row = fidx >> 6;
        int col = fidx & 63;
        float4 v = make_float4(0.f, 0.f, 0.f, 0.f);
        if (n0 + row < N) v = *reinterpret_cast<const float4*>(&h2[(size_t)(n0 + row) * 64 + col]);
        *reinterpret_cast<float4*>(&hs[row][col]) = v;
    }
    __syncthreads();
    int node = t >> 2, j4 = t & 3;
    float4 acc = make_float4(0.f, 0.f, 0.f, 0.f);
    #pragma unroll
    for (int k = 0; k < 64; ++k) {
        float hk = hs[node][k];
        float4 w = *reinterpret_cast<const float4*>(&ws[k * 16 + j4 * 4]);
        acc.x = fmaf(hk, w.x, acc.x);
        acc.y = fmaf(hk, w.y, acc.y);
        acc.z = fmaf(hk, w.z, acc.z);
        acc.w = fmaf(hk, w.w, acc.w);
    }
    float4 asv = *reinterpret_cast<const float4*>(&a2_src[j4 * 4]);
    float4 adv = *reinterpret_cast<const float4*>(&a2_dst[j4 * 4]);
    float ps = acc.x * asv.x + acc.y * asv.y + acc.z * asv.z + acc.w * asv.w;
    float pd = acc.x * adv.x + acc.y * adv.y + acc.z * adv.z + acc.w * adv.w;
    ps += __shfl_xor(ps, 1); ps += __shfl_xor(ps, 2);
    pd += __shfl_xor(pd, 1); pd += __shfl_xor(pd, 2);
    int gnode = n0 + node;
    if (gnode < N) {
        ushort4 p;
        p.x = f2bf(acc.x); p.y = f2bf(acc.y);
        p.z = f2bf(acc.z); p.w = f2bf(acc.w);
        *reinterpret_cast<ushort4*>(&g2b[(size_t)gnode * 16 + j4 * 4]) = p;
        if (j4 == 0) { as2[gnode] = ps; ad2[gnode] = pd; }
    }
}

// ---------------- layer-2 gather: per-lane exp (dedup), + bias + log_softmax ----------------
// 64-edge batches: each lane owns one edge's exp; accumulation shfl-broadcasts (x, src)
__global__ __launch_bounds__(128) void gat2_kernel(const u16* __restrict__ g2b,
                                                   const float* __restrict__ as2,
                                                   const float* __restrict__ ad2,
                                                   const int* __restrict__ row_ptr,
                                                   const int* __restrict__ csr_src,
                                                   const float* __restrict__ b2,
                                                   float* __restrict__ out, int N) {
    int dst = blockIdx.x * 2 + (threadIdx.x >> 6);
    if (dst >= N) return;
    int lane = threadIdx.x & 63;
    int slot = lane >> 3, jd = lane & 7;
    float ad = ad2[dst];
    int start = row_ptr[dst], end = row_ptr[dst + 1];
    float acc0 = 0.f, acc1 = 0.f, ssum = 0.f;
    for (int i = start; i < end; i += 64) {
        int nb = end - i; if (nb > 64) nb = 64;
        bool lv = lane < nb;
        int sv = lv ? csr_src[i + lane] : 0;
        float a = lv ? as2[sv] : 0.f;
        float e = a + ad;
        e = fmaxf(e, NEG_SLOPE * e);
        float xx = lv ? __expf(e) : 0.f;
        ssum += xx;                                   // per-lane; full reduce at end
        for (int k = 0; k < nb; k += 8) {
            int idx = k + slot;                       // < 64 always; xx[idx]==0 if idx>=nb
            float xb = __shfl(xx, idx);
            int sb = __shfl(sv, idx);
            unsigned w = *reinterpret_cast<const unsigned*>(&g2b[(size_t)sb * 16 + jd * 2]);
            acc0 = fmaf(xb, bflo(w), acc0);
            acc1 = fmaf(xb, bfhi(w), acc1);
        }
    }
    acc0 += __shfl_xor(acc0, 8); acc0 += __shfl_xor(acc0, 16); acc0 += __shfl_xor(acc0, 32);
    acc1 += __shfl_xor(acc1, 8); acc1 += __shfl_xor(acc1, 16); acc1 += __shfl_xor(acc1, 32);
    ssum += __shfl_xor(ssum, 1); ssum += __shfl_xor(ssum, 2); ssum += __shfl_xor(ssum, 4);
    ssum += __shfl_xor(ssum, 8); ssum += __shfl_xor(ssum, 16); ssum += __shfl_xor(ssum, 32);
    float inv = 1.f / (ssum + EPS_F);
    float2 bb = *reinterpret_cast<const float2*>(&b2[jd * 2]);
    float v0 = acc0 * inv + bb.x;
    float v1 = acc1 * inv + bb.y;
    float mm = fmaxf(v0, v1);
    mm = fmaxf(mm, __shfl_xor(mm, 1));
    mm = fmaxf(mm, __shfl_xor(mm, 2));
    mm = fmaxf(mm, __shfl_xor(mm, 4));
    float es = __expf(v0 - mm) + __expf(v1 - mm);
    es += __shfl_xor(es, 1); es += __shfl_xor(es, 2); es += __shfl_xor(es, 4);
    float lse = mm + __logf(es);
    if (lane < 8) {
        *reinterpret_cast<float2*>(&out[(size_t)dst * 16 + jd * 2]) = make_float2(v0, v1);
        *reinterpret_cast<float2*>(&out[(size_t)N * 16 + (size_t)dst * 16 + jd * 2]) =
            make_float2(v0 - lse, v1 - lse);
    }
}

extern "C" void kernel_launch(void* const* d_in, const int* in_sizes, int n_in,
                              void* d_out, int out_size, void* d_ws, size_t ws_size,
                              hipStream_t stream) {
    const float* x      = (const float*)d_in[0];
    const int*   eidx   = (const int*)d_in[1];
    const float* W1     = (const float*)d_in[2];
    const float* a1_src = (const float*)d_in[3];
    const float* a1_dst = (const float*)d_in[4];
    const float* b1     = (const float*)d_in[5];
    const float* W2     = (const float*)d_in[6];
    const float* a2_src = (const float*)d_in[7];
    const float* a2_dst = (const float*)d_in[8];
    const float* b2     = (const float*)d_in[9];

    const int N = in_sizes[0] / 256;
    const int E = in_sizes[1] / 2;
    const int K = (N + 511) >> 9;
    const int* esrc = eidx;
    const int* edst = eidx + E;

    char* ws = (char*)d_ws;
    size_t off = 0;
    auto alloc = [&](size_t bytes) -> void* {
        void* p = ws + off;
        off += (bytes + 255) & ~size_t(255);
        return p;
    };
    u16* h1b         = (u16*)alloc((size_t)N * 64 * 2);
    u16* w1t         = (u16*)alloc((size_t)64 * 256 * 2);
    float* as1       = (float*)alloc((size_t)N * 8 * 4);
    float* ad1       = (float*)alloc((size_t)N * 8 * 4);
    float* h2        = (float*)alloc((size_t)N * 64 * 4);
    u16* g2b         = (u16*)alloc((size_t)N * 16 * 2);
    float* as2       = (float*)alloc((size_t)N * 4);
    float* ad2       = (float*)alloc((size_t)N * 4);
    int* row_ptr     = (int*)alloc((size_t)(N + 1) * 4);
    int* csr_src     = (int*)alloc((size_t)E * 4);
    int* cursor      = (int*)alloc((size_t)K_MAX * 4);
    unsigned* bins   = (unsigned*)alloc((size_t)K_MAX * BCAP * 4);

    const int G1 = (N + 63) / 64;
    const int GB = (E + CHUNK - 1) / CHUNK;

    prep_w1t_kernel<<<64, 256, 0, stream>>>(W1, w1t, cursor);
    front_kernel<<<G1 + GB, 256, 0, stream>>>(x, w1t, a1_src, a1_dst, h1b, as1, ad1, N,
                                              esrc, edst, cursor, bins, E, K, G1, GB);
    csr_kernel<<<K, 256, 0, stream>>>(bins, cursor, row_ptr, csr_src, N, K, E);
    gat1_kernel<<<(N + 1) / 2, 128, 0, stream>>>(h1b, as1, ad1, row_ptr, csr_src, b1, h2, N);
    gemm2_kernel<<<(N + 63) / 64, 256, 0, stream>>>(h2, W2, a2_src, a2_dst, g2b, as2, ad2, N);
    gat2_kernel<<<(N + 1) / 2, 128, 0, stream>>>(g2b, as2, ad2, row_ptr, csr_src, b2, (float*)d_out, N);
}